// Round 1
// baseline (2974.731 us; speedup 1.0000x reference)
//
#include <hip/hip_runtime.h>
#include <hip/hip_bf16.h>
#include <math.h>

#define BB 32
#define SS 1024
#define DD 1024

// ---------------------------------------------------------------------------
// Kernel 1: y[m,n] = sum_k x[m,k] * W[n,k] + bias[n]   (torch Linear)
// M = B*S = 32768, K = D = 1024, N = D = 1024.
// 64x64 tile, 256 threads, 4x4 micro-tile, LDS staged (pad 68 keeps float4
// alignment (272B rows) and reduces bank conflicts to free 2-way).
// ---------------------------------------------------------------------------
__global__ __launch_bounds__(256) void linear_qk(
    const float* __restrict__ x, const float* __restrict__ W,
    const float* __restrict__ bias, float* __restrict__ y)
{
    __shared__ float As[16][68];
    __shared__ float Ws[16][68];
    const int tid = threadIdx.x;
    const int tx = tid & 15, ty = tid >> 4;
    const int m0 = blockIdx.y * 64;
    const int n0 = blockIdx.x * 64;

    float acc[4][4] = {};

    for (int k0 = 0; k0 < DD; k0 += 16) {
        #pragma unroll
        for (int i = 0; i < 4; ++i) {
            int idx = i * 256 + tid;
            int kk = idx & 15, mm = idx >> 4;
            As[kk][mm] = x[(size_t)(m0 + mm) * DD + (k0 + kk)];
            Ws[kk][mm] = W[(size_t)(n0 + mm) * DD + (k0 + kk)];
        }
        __syncthreads();
        #pragma unroll
        for (int kk = 0; kk < 16; ++kk) {
            float4 a = *(const float4*)&As[kk][ty * 4];
            float4 w = *(const float4*)&Ws[kk][tx * 4];
            acc[0][0] += a.x * w.x; acc[0][1] += a.x * w.y; acc[0][2] += a.x * w.z; acc[0][3] += a.x * w.w;
            acc[1][0] += a.y * w.x; acc[1][1] += a.y * w.y; acc[1][2] += a.y * w.z; acc[1][3] += a.y * w.w;
            acc[2][0] += a.z * w.x; acc[2][1] += a.z * w.y; acc[2][2] += a.z * w.z; acc[2][3] += a.z * w.w;
            acc[3][0] += a.w * w.x; acc[3][1] += a.w * w.y; acc[3][2] += a.w * w.z; acc[3][3] += a.w * w.w;
        }
        __syncthreads();
    }

    #pragma unroll
    for (int i = 0; i < 4; ++i) {
        int m = m0 + ty * 4 + i;
        #pragma unroll
        for (int j = 0; j < 4; ++j) {
            int n = n0 + tx * 4 + j;
            y[(size_t)m * DD + n] = acc[i][j] + bias[n];
        }
    }
}

// ---------------------------------------------------------------------------
// Kernel 2: s[b,srow] += sum_t tanh(q[b,srow,:] . k[b,t,:]) * v[t]
// Per-batch 1024x1024x1024 GEMM with fused tanh epilogue + row reduction.
// Grid: (S/64 t-tiles, S/64 s-tiles, B). atomicAdd 64 partials per block.
// ---------------------------------------------------------------------------
__global__ __launch_bounds__(256) void scores_reduce(
    const float* __restrict__ q, const float* __restrict__ k,
    const float* __restrict__ v, float* __restrict__ s_out)
{
    __shared__ float As[16][68];
    __shared__ float Ws[16][68];
    __shared__ float red[64][17];

    const int tid = threadIdx.x;
    const int tx = tid & 15, ty = tid >> 4;
    const int b  = blockIdx.z;
    const int s0 = blockIdx.y * 64;
    const int t0 = blockIdx.x * 64;

    const float* qb = q + (size_t)b * SS * DD;
    const float* kb = k + (size_t)b * SS * DD;

    float acc[4][4] = {};

    for (int k0 = 0; k0 < DD; k0 += 16) {
        #pragma unroll
        for (int i = 0; i < 4; ++i) {
            int idx = i * 256 + tid;
            int kk = idx & 15, mm = idx >> 4;
            As[kk][mm] = qb[(size_t)(s0 + mm) * DD + (k0 + kk)];
            Ws[kk][mm] = kb[(size_t)(t0 + mm) * DD + (k0 + kk)];
        }
        __syncthreads();
        #pragma unroll
        for (int kk = 0; kk < 16; ++kk) {
            float4 a = *(const float4*)&As[kk][ty * 4];
            float4 w = *(const float4*)&Ws[kk][tx * 4];
            acc[0][0] += a.x * w.x; acc[0][1] += a.x * w.y; acc[0][2] += a.x * w.z; acc[0][3] += a.x * w.w;
            acc[1][0] += a.y * w.x; acc[1][1] += a.y * w.y; acc[1][2] += a.y * w.z; acc[1][3] += a.y * w.w;
            acc[2][0] += a.z * w.x; acc[2][1] += a.z * w.y; acc[2][2] += a.z * w.z; acc[2][3] += a.z * w.w;
            acc[3][0] += a.w * w.x; acc[3][1] += a.w * w.y; acc[3][2] += a.w * w.z; acc[3][3] += a.w * w.w;
        }
        __syncthreads();
    }

    // epilogue: tanh, multiply by v[t], partial row sums
    float vj[4];
    #pragma unroll
    for (int j = 0; j < 4; ++j) vj[j] = v[t0 + tx * 4 + j];

    #pragma unroll
    for (int i = 0; i < 4; ++i) {
        float p = 0.f;
        #pragma unroll
        for (int j = 0; j < 4; ++j) p += tanhf(acc[i][j]) * vj[j];
        red[ty * 4 + i][tx] = p;
    }
    __syncthreads();
    if (tid < 64) {
        float tot = 0.f;
        #pragma unroll
        for (int c = 0; c < 16; ++c) tot += red[tid][c];
        atomicAdd(&s_out[b * SS + s0 + tid], tot);
    }
}

// ---------------------------------------------------------------------------
// Kernel 3: softmax over S per batch. One block per batch, 256 threads x4.
// ---------------------------------------------------------------------------
__global__ __launch_bounds__(256) void softmax_rows(
    const float* __restrict__ sbuf, float* __restrict__ wbuf)
{
    const int b = blockIdx.x, tid = threadIdx.x;
    const int wave = tid >> 6, lane = tid & 63;
    __shared__ float redm[4];
    __shared__ float redsum[4];

    float vals[4];
    float mx = -1e30f;
    #pragma unroll
    for (int i = 0; i < 4; ++i) {
        vals[i] = sbuf[b * SS + i * 256 + tid];
        mx = fmaxf(mx, vals[i]);
    }
    #pragma unroll
    for (int off = 32; off; off >>= 1) mx = fmaxf(mx, __shfl_xor(mx, off));
    if (lane == 0) redm[wave] = mx;
    __syncthreads();
    mx = fmaxf(fmaxf(redm[0], redm[1]), fmaxf(redm[2], redm[3]));

    float sum = 0.f;
    #pragma unroll
    for (int i = 0; i < 4; ++i) { vals[i] = expf(vals[i] - mx); sum += vals[i]; }
    #pragma unroll
    for (int off = 32; off; off >>= 1) sum += __shfl_xor(sum, off);
    if (lane == 0) redsum[wave] = sum;
    __syncthreads();
    sum = redsum[0] + redsum[1] + redsum[2] + redsum[3];

    float inv = 1.0f / sum;
    #pragma unroll
    for (int i = 0; i < 4; ++i) wbuf[b * SS + i * 256 + tid] = vals[i] * inv;
}

// ---------------------------------------------------------------------------
// Kernel 4: out[b,d] = sum_s w[b,s] * x[b,s,d]
// ---------------------------------------------------------------------------
__global__ __launch_bounds__(256) void weighted_sum(
    const float* __restrict__ x, const float* __restrict__ wbuf,
    float* __restrict__ out)
{
    __shared__ float wl[SS];
    const int b = blockIdx.y;
    const int d = blockIdx.x * 256 + threadIdx.x;
    for (int i = threadIdx.x; i < SS; i += 256) wl[i] = wbuf[b * SS + i];
    __syncthreads();

    const float* xb = x + (size_t)b * SS * DD + d;
    float acc = 0.f;
    for (int s = 0; s < SS; ++s) acc += wl[s] * xb[(size_t)s * DD];
    out[b * DD + d] = acc;
}

// ---------------------------------------------------------------------------
extern "C" void kernel_launch(void* const* d_in, const int* in_sizes, int n_in,
                              void* d_out, int out_size, void* d_ws, size_t ws_size,
                              hipStream_t stream) {
    const float* x  = (const float*)d_in[0];
    const float* Wq = (const float*)d_in[1];
    const float* bq = (const float*)d_in[2];
    const float* Wk = (const float*)d_in[3];
    const float* bk = (const float*)d_in[4];
    const float* v  = (const float*)d_in[5];
    float* out = (float*)d_out;

    // workspace layout (floats): q [B*S*D], k [B*S*D], s [B*S], w [B*S]
    float* q    = (float*)d_ws;
    float* k    = q + (size_t)BB * SS * DD;
    float* sbuf = k + (size_t)BB * SS * DD;
    float* wbuf = sbuf + BB * SS;

    // s is accumulated via atomics -> must be zeroed every call
    hipMemsetAsync(sbuf, 0, (size_t)BB * SS * sizeof(float), stream);

    dim3 blk(256);
    dim3 g1(DD / 64, (BB * SS) / 64);          // 16 x 512
    linear_qk<<<g1, blk, 0, stream>>>(x, Wq, bq, q);
    linear_qk<<<g1, blk, 0, stream>>>(x, Wk, bk, k);

    dim3 g2(SS / 64, SS / 64, BB);             // 16 x 16 x 32
    scores_reduce<<<g2, blk, 0, stream>>>(q, k, v, sbuf);

    softmax_rows<<<BB, blk, 0, stream>>>(sbuf, wbuf);

    dim3 g4(DD / 256, BB);                     // 4 x 32
    weighted_sum<<<g4, blk, 0, stream>>>(x, wbuf, out);
}

// Round 2
// 1093.320 us; speedup vs baseline: 2.7208x; 2.7208x over previous
//
#include <hip/hip_runtime.h>
#include <hip/hip_bf16.h>
#include <math.h>

#define BB 32
#define SS 1024
#define DD 1024

typedef __bf16 bf16_t;
typedef __bf16 bf16x4 __attribute__((ext_vector_type(4)));
typedef __bf16 bf16x8 __attribute__((ext_vector_type(8)));
typedef float f32x4 __attribute__((ext_vector_type(4)));

// async global -> LDS, 16B per lane. lds pointer must be wave-uniform;
// HW writes lds_base + lane*16.
__device__ __forceinline__ void gload16(const void* g, void* lds_uniform) {
    __builtin_amdgcn_global_load_lds(
        (const __attribute__((address_space(1))) void*)g,
        (__attribute__((address_space(3))) void*)lds_uniform, 16, 0, 0);
}

// ---------------------------------------------------------------------------
// split fp32 -> (hi, lo) bf16.  hi = bf16(f), lo = bf16(f - hi).
// ---------------------------------------------------------------------------
__global__ __launch_bounds__(256) void split_fp32(
    const float* __restrict__ src, bf16_t* __restrict__ hi,
    bf16_t* __restrict__ lo, int n4)
{
    for (int idx = blockIdx.x * 256 + threadIdx.x; idx < n4;
         idx += gridDim.x * 256) {
        float4 f = ((const float4*)src)[idx];
        bf16x4 h, l;
        h.x = (bf16_t)f.x; h.y = (bf16_t)f.y; h.z = (bf16_t)f.z; h.w = (bf16_t)f.w;
        l.x = (bf16_t)(f.x - (float)h.x);
        l.y = (bf16_t)(f.y - (float)h.y);
        l.z = (bf16_t)(f.z - (float)h.z);
        l.w = (bf16_t)(f.w - (float)h.w);
        ((bf16x4*)hi)[idx] = h;
        ((bf16x4*)lo)[idx] = l;
    }
}

// ---------------------------------------------------------------------------
// Split-precision MFMA GEMM: C[m,n] = sum_k A[m,k]*B[n,k] (+bias), where
// A = Ah+Al, B = Bh+Bl in bf16 pairs. 3 passes: Ah*Bh + Ah*Bl + Al*Bh.
// 128x128 tile, 4 waves (2x2), each wave 4x4 frags of 16x16x32.
// Epilogue writes out as hi/lo bf16 pair (consumed by scores GEMM).
// ---------------------------------------------------------------------------
__global__ __launch_bounds__(256) void gemm_proj_split(
    const bf16_t* __restrict__ Ah_g, const bf16_t* __restrict__ Al_g,
    const bf16_t* __restrict__ Bh_g, const bf16_t* __restrict__ Bl_g,
    const float* __restrict__ bias,
    bf16_t* __restrict__ out_hi, bf16_t* __restrict__ out_lo)
{
    __shared__ __align__(16) bf16_t Ash[128 * 32];
    __shared__ __align__(16) bf16_t Bsh[128 * 32];
    const int tid = threadIdx.x;
    const int lane = tid & 63, wid = tid >> 6;
    const int wr = wid >> 1, wc = wid & 1;
    const int m0 = blockIdx.y * 128, n0 = blockIdx.x * 128;

    const int trow = tid >> 2;        // 0..63
    const int tcol = (tid & 3) * 8;   // element col within k-tile
    char* AldsW = (char*)Ash + wid * 1024;  // wave-uniform LDS base
    char* BldsW = (char*)Bsh + wid * 1024;

    f32x4 acc[4][4] = {};

    for (int pass = 0; pass < 3; ++pass) {
        const bf16_t* As = (pass < 2) ? Ah_g : Al_g;
        const bf16_t* Bs = (pass == 1) ? Bl_g : Bh_g;
        for (int k0 = 0; k0 < DD; k0 += 32) {
            __syncthreads();  // previous compute done before overwrite
            gload16(As + (size_t)(m0 + trow) * DD + k0 + tcol, AldsW);
            gload16(As + (size_t)(m0 + 64 + trow) * DD + k0 + tcol, AldsW + 4096);
            gload16(Bs + (size_t)(n0 + trow) * DD + k0 + tcol, BldsW);
            gload16(Bs + (size_t)(n0 + 64 + trow) * DD + k0 + tcol, BldsW + 4096);
            __syncthreads();  // compiler drains vmcnt before barrier

            const char* Ab = (const char*)Ash;
            const char* Bb = (const char*)Bsh;
            const int klane = (lane >> 4) * 16;  // byte offset in 64B row
            const int rA = wr * 64 + (lane & 15);
            const int rB = wc * 64 + (lane & 15);
            bf16x8 af[4], bfr[4];
            #pragma unroll
            for (int i = 0; i < 4; ++i)
                af[i] = *(const bf16x8*)(Ab + (rA + i * 16) * 64 + klane);
            #pragma unroll
            for (int j = 0; j < 4; ++j)
                bfr[j] = *(const bf16x8*)(Bb + (rB + j * 16) * 64 + klane);
            #pragma unroll
            for (int i = 0; i < 4; ++i)
                #pragma unroll
                for (int j = 0; j < 4; ++j)
                    acc[i][j] = __builtin_amdgcn_mfma_f32_16x16x32_bf16(
                        af[i], bfr[j], acc[i][j], 0, 0, 0);
        }
    }

    // epilogue: C/D frag layout col=lane&15, row=(lane>>4)*4+r
    const int rbase = (lane >> 4) * 4;
    const int cbase = lane & 15;
    #pragma unroll
    for (int i = 0; i < 4; ++i) {
        #pragma unroll
        for (int j = 0; j < 4; ++j) {
            const int n = n0 + wc * 64 + j * 16 + cbase;
            const float bv = bias[n];
            #pragma unroll
            for (int r = 0; r < 4; ++r) {
                const int m = m0 + wr * 64 + i * 16 + rbase + r;
                float valf = acc[i][j][r] + bv;
                bf16_t h = (bf16_t)valf;
                out_hi[(size_t)m * DD + n] = h;
                out_lo[(size_t)m * DD + n] = (bf16_t)(valf - (float)h);
            }
        }
    }
}

// ---------------------------------------------------------------------------
// Scores GEMM (per batch): s[b,srow] += sum_t tanh(q.k) * v[t]
// Same split 3-pass MFMA body; epilogue fuses tanh, *v, 16-lane shuffle
// reduce, atomicAdd.
// ---------------------------------------------------------------------------
__global__ __launch_bounds__(256) void gemm_scores_split(
    const bf16_t* __restrict__ qh, const bf16_t* __restrict__ ql,
    const bf16_t* __restrict__ kh, const bf16_t* __restrict__ kl,
    const float* __restrict__ v, float* __restrict__ sbuf)
{
    __shared__ __align__(16) bf16_t Ash[128 * 32];
    __shared__ __align__(16) bf16_t Bsh[128 * 32];
    const int tid = threadIdx.x;
    const int lane = tid & 63, wid = tid >> 6;
    const int wr = wid >> 1, wc = wid & 1;
    const int b  = blockIdx.z;
    const int s0 = blockIdx.y * 128, t0 = blockIdx.x * 128;
    const size_t boff = (size_t)b * SS * DD;

    const int trow = tid >> 2;
    const int tcol = (tid & 3) * 8;
    char* AldsW = (char*)Ash + wid * 1024;
    char* BldsW = (char*)Bsh + wid * 1024;

    f32x4 acc[4][4] = {};

    for (int pass = 0; pass < 3; ++pass) {
        const bf16_t* As = ((pass < 2) ? qh : ql) + boff;
        const bf16_t* Bs = ((pass == 1) ? kl : kh) + boff;
        for (int k0 = 0; k0 < DD; k0 += 32) {
            __syncthreads();
            gload16(As + (size_t)(s0 + trow) * DD + k0 + tcol, AldsW);
            gload16(As + (size_t)(s0 + 64 + trow) * DD + k0 + tcol, AldsW + 4096);
            gload16(Bs + (size_t)(t0 + trow) * DD + k0 + tcol, BldsW);
            gload16(Bs + (size_t)(t0 + 64 + trow) * DD + k0 + tcol, BldsW + 4096);
            __syncthreads();

            const char* Ab = (const char*)Ash;
            const char* Bb = (const char*)Bsh;
            const int klane = (lane >> 4) * 16;
            const int rA = wr * 64 + (lane & 15);
            const int rB = wc * 64 + (lane & 15);
            bf16x8 af[4], bfr[4];
            #pragma unroll
            for (int i = 0; i < 4; ++i)
                af[i] = *(const bf16x8*)(Ab + (rA + i * 16) * 64 + klane);
            #pragma unroll
            for (int j = 0; j < 4; ++j)
                bfr[j] = *(const bf16x8*)(Bb + (rB + j * 16) * 64 + klane);
            #pragma unroll
            for (int i = 0; i < 4; ++i)
                #pragma unroll
                for (int j = 0; j < 4; ++j)
                    acc[i][j] = __builtin_amdgcn_mfma_f32_16x16x32_bf16(
                        af[i], bfr[j], acc[i][j], 0, 0, 0);
        }
    }

    // epilogue: per output row, sum_j tanh(score)*v[t]; reduce across the
    // 16 column-lanes (xor 1,2,4,8 stays within the group; lane>>4 invariant)
    const int rbase = (lane >> 4) * 4;
    const int cbase = lane & 15;
    #pragma unroll
    for (int i = 0; i < 4; ++i) {
        #pragma unroll
        for (int r = 0; r < 4; ++r) {
            float p = 0.f;
            #pragma unroll
            for (int j = 0; j < 4; ++j) {
                const int t = t0 + wc * 64 + j * 16 + cbase;
                p += tanhf(acc[i][j][r]) * v[t];
            }
            p += __shfl_xor(p, 1);
            p += __shfl_xor(p, 2);
            p += __shfl_xor(p, 4);
            p += __shfl_xor(p, 8);
            if (cbase == 0) {
                const int srow = s0 + wr * 64 + i * 16 + rbase + r;
                atomicAdd(&sbuf[b * SS + srow], p);
            }
        }
    }
}

// ---------------------------------------------------------------------------
// softmax over S per batch (unchanged from round 1)
// ---------------------------------------------------------------------------
__global__ __launch_bounds__(256) void softmax_rows(
    const float* __restrict__ sbuf, float* __restrict__ wbuf)
{
    const int b = blockIdx.x, tid = threadIdx.x;
    const int wave = tid >> 6, lane = tid & 63;
    __shared__ float redm[4];
    __shared__ float redsum[4];

    float vals[4];
    float mx = -1e30f;
    #pragma unroll
    for (int i = 0; i < 4; ++i) {
        vals[i] = sbuf[b * SS + i * 256 + tid];
        mx = fmaxf(mx, vals[i]);
    }
    #pragma unroll
    for (int off = 32; off; off >>= 1) mx = fmaxf(mx, __shfl_xor(mx, off));
    if (lane == 0) redm[wave] = mx;
    __syncthreads();
    mx = fmaxf(fmaxf(redm[0], redm[1]), fmaxf(redm[2], redm[3]));

    float sum = 0.f;
    #pragma unroll
    for (int i = 0; i < 4; ++i) { vals[i] = expf(vals[i] - mx); sum += vals[i]; }
    #pragma unroll
    for (int off = 32; off; off >>= 1) sum += __shfl_xor(sum, off);
    if (lane == 0) redsum[wave] = sum;
    __syncthreads();
    sum = redsum[0] + redsum[1] + redsum[2] + redsum[3];

    float inv = 1.0f / sum;
    #pragma unroll
    for (int i = 0; i < 4; ++i) wbuf[b * SS + i * 256 + tid] = vals[i] * inv;
}

// ---------------------------------------------------------------------------
// out[b,d] = sum_s w[b,s] * x[b,s,d]  (unchanged from round 1)
// ---------------------------------------------------------------------------
__global__ __launch_bounds__(256) void weighted_sum(
    const float* __restrict__ x, const float* __restrict__ wbuf,
    float* __restrict__ out)
{
    __shared__ float wl[SS];
    const int b = blockIdx.y;
    const int d = blockIdx.x * 256 + threadIdx.x;
    for (int i = threadIdx.x; i < SS; i += 256) wl[i] = wbuf[b * SS + i];
    __syncthreads();

    const float* xb = x + (size_t)b * SS * DD + d;
    float acc = 0.f;
    for (int s = 0; s < SS; ++s) acc += wl[s] * xb[(size_t)s * DD];
    out[b * DD + d] = acc;
}

// ======================= round-1 fp32 fallback kernels ======================
__global__ __launch_bounds__(256) void linear_qk(
    const float* __restrict__ x, const float* __restrict__ W,
    const float* __restrict__ bias, float* __restrict__ y)
{
    __shared__ float As[16][68];
    __shared__ float Ws[16][68];
    const int tid = threadIdx.x;
    const int tx = tid & 15, ty = tid >> 4;
    const int m0 = blockIdx.y * 64;
    const int n0 = blockIdx.x * 64;
    float acc[4][4] = {};
    for (int k0 = 0; k0 < DD; k0 += 16) {
        #pragma unroll
        for (int i = 0; i < 4; ++i) {
            int idx = i * 256 + tid;
            int kk = idx & 15, mm = idx >> 4;
            As[kk][mm] = x[(size_t)(m0 + mm) * DD + (k0 + kk)];
            Ws[kk][mm] = W[(size_t)(n0 + mm) * DD + (k0 + kk)];
        }
        __syncthreads();
        #pragma unroll
        for (int kk = 0; kk < 16; ++kk) {
            float4 a = *(const float4*)&As[kk][ty * 4];
            float4 w = *(const float4*)&Ws[kk][tx * 4];
            acc[0][0] += a.x * w.x; acc[0][1] += a.x * w.y; acc[0][2] += a.x * w.z; acc[0][3] += a.x * w.w;
            acc[1][0] += a.y * w.x; acc[1][1] += a.y * w.y; acc[1][2] += a.y * w.z; acc[1][3] += a.y * w.w;
            acc[2][0] += a.z * w.x; acc[2][1] += a.z * w.y; acc[2][2] += a.z * w.z; acc[2][3] += a.z * w.w;
            acc[3][0] += a.w * w.x; acc[3][1] += a.w * w.y; acc[3][2] += a.w * w.z; acc[3][3] += a.w * w.w;
        }
        __syncthreads();
    }
    #pragma unroll
    for (int i = 0; i < 4; ++i) {
        int m = m0 + ty * 4 + i;
        #pragma unroll
        for (int j = 0; j < 4; ++j) {
            int n = n0 + tx * 4 + j;
            y[(size_t)m * DD + n] = acc[i][j] + bias[n];
        }
    }
}

__global__ __launch_bounds__(256) void scores_reduce(
    const float* __restrict__ q, const float* __restrict__ k,
    const float* __restrict__ v, float* __restrict__ s_out)
{
    __shared__ float As[16][68];
    __shared__ float Ws[16][68];
    __shared__ float red[64][17];
    const int tid = threadIdx.x;
    const int tx = tid & 15, ty = tid >> 4;
    const int b  = blockIdx.z;
    const int s0 = blockIdx.y * 64;
    const int t0 = blockIdx.x * 64;
    const float* qb = q + (size_t)b * SS * DD;
    const float* kb = k + (size_t)b * SS * DD;
    float acc[4][4] = {};
    for (int k0 = 0; k0 < DD; k0 += 16) {
        #pragma unroll
        for (int i = 0; i < 4; ++i) {
            int idx = i * 256 + tid;
            int kk = idx & 15, mm = idx >> 4;
            As[kk][mm] = qb[(size_t)(s0 + mm) * DD + (k0 + kk)];
            Ws[kk][mm] = kb[(size_t)(t0 + mm) * DD + (k0 + kk)];
        }
        __syncthreads();
        #pragma unroll
        for (int kk = 0; kk < 16; ++kk) {
            float4 a = *(const float4*)&As[kk][ty * 4];
            float4 w = *(const float4*)&Ws[kk][tx * 4];
            acc[0][0] += a.x * w.x; acc[0][1] += a.x * w.y; acc[0][2] += a.x * w.z; acc[0][3] += a.x * w.w;
            acc[1][0] += a.y * w.x; acc[1][1] += a.y * w.y; acc[1][2] += a.y * w.z; acc[1][3] += a.y * w.w;
            acc[2][0] += a.z * w.x; acc[2][1] += a.z * w.y; acc[2][2] += a.z * w.z; acc[2][3] += a.z * w.w;
            acc[3][0] += a.w * w.x; acc[3][1] += a.w * w.y; acc[3][2] += a.w * w.z; acc[3][3] += a.w * w.w;
        }
        __syncthreads();
    }
    float vj[4];
    #pragma unroll
    for (int j = 0; j < 4; ++j) vj[j] = v[t0 + tx * 4 + j];
    #pragma unroll
    for (int i = 0; i < 4; ++i) {
        float p = 0.f;
        #pragma unroll
        for (int j = 0; j < 4; ++j) p += tanhf(acc[i][j]) * vj[j];
        red[ty * 4 + i][tx] = p;
    }
    __syncthreads();
    if (tid < 64) {
        float tot = 0.f;
        #pragma unroll
        for (int c = 0; c < 16; ++c) tot += red[tid][c];
        atomicAdd(&s_out[b * SS + s0 + tid], tot);
    }
}

// ---------------------------------------------------------------------------
extern "C" void kernel_launch(void* const* d_in, const int* in_sizes, int n_in,
                              void* d_out, int out_size, void* d_ws, size_t ws_size,
                              hipStream_t stream) {
    const float* x  = (const float*)d_in[0];
    const float* Wq = (const float*)d_in[1];
    const float* bq = (const float*)d_in[2];
    const float* Wk = (const float*)d_in[3];
    const float* bk = (const float*)d_in[4];
    const float* v  = (const float*)d_in[5];
    float* out = (float*)d_out;

    const size_t nx = (size_t)BB * SS * DD;   // 33,554,432
    const size_t nw = (size_t)DD * DD;        // 1,048,576
    const size_t need = nx * 2 * 6 + nw * 2 * 4 + (size_t)BB * SS * 4 * 2;

    dim3 blk(256);

    if (ws_size >= need) {
        // ---- fast path: split-precision bf16 MFMA ----
        char* p = (char*)d_ws;
        bf16_t* xh  = (bf16_t*)p;            p += nx * 2;
        bf16_t* xl  = (bf16_t*)p;            p += nx * 2;
        bf16_t* qh  = (bf16_t*)p;            p += nx * 2;
        bf16_t* ql  = (bf16_t*)p;            p += nx * 2;
        bf16_t* kh  = (bf16_t*)p;            p += nx * 2;
        bf16_t* kl  = (bf16_t*)p;            p += nx * 2;
        bf16_t* wqh = (bf16_t*)p;            p += nw * 2;
        bf16_t* wql = (bf16_t*)p;            p += nw * 2;
        bf16_t* wkh = (bf16_t*)p;            p += nw * 2;
        bf16_t* wkl = (bf16_t*)p;            p += nw * 2;
        float*  sbuf = (float*)p;            p += (size_t)BB * SS * 4;
        float*  wbuf = (float*)p;

        hipMemsetAsync(sbuf, 0, (size_t)BB * SS * sizeof(float), stream);

        split_fp32<<<2048, blk, 0, stream>>>(x,  xh,  xl,  (int)(nx / 4));
        split_fp32<<<512,  blk, 0, stream>>>(Wq, wqh, wql, (int)(nw / 4));
        split_fp32<<<512,  blk, 0, stream>>>(Wk, wkh, wkl, (int)(nw / 4));

        dim3 gp(DD / 128, (BB * SS) / 128);   // 8 x 256
        gemm_proj_split<<<gp, blk, 0, stream>>>(xh, xl, wqh, wql, bq, qh, ql);
        gemm_proj_split<<<gp, blk, 0, stream>>>(xh, xl, wkh, wkl, bk, kh, kl);

        dim3 gs(SS / 128, SS / 128, BB);      // 8 x 8 x 32
        gemm_scores_split<<<gs, blk, 0, stream>>>(qh, ql, kh, kl, v, sbuf);

        softmax_rows<<<BB, blk, 0, stream>>>(sbuf, wbuf);
        dim3 g4(DD / 256, BB);
        weighted_sum<<<g4, blk, 0, stream>>>(x, wbuf, out);
    } else {
        // ---- fallback: round-1 fp32 path ----
        float* q    = (float*)d_ws;
        float* kk   = q + nx;
        float* sbuf = kk + nx;
        float* wbuf = sbuf + BB * SS;

        hipMemsetAsync(sbuf, 0, (size_t)BB * SS * sizeof(float), stream);

        dim3 g1(DD / 64, (BB * SS) / 64);
        linear_qk<<<g1, blk, 0, stream>>>(x, Wq, bq, q);
        linear_qk<<<g1, blk, 0, stream>>>(x, Wk, bk, kk);
        dim3 g2(SS / 64, SS / 64, BB);
        scores_reduce<<<g2, blk, 0, stream>>>(q, kk, v, sbuf);
        softmax_rows<<<BB, blk, 0, stream>>>(sbuf, wbuf);
        dim3 g4(DD / 256, BB);
        weighted_sum<<<g4, blk, 0, stream>>>(x, wbuf, out);
    }
}

// Round 3
// 1074.062 us; speedup vs baseline: 2.7696x; 1.0179x over previous
//
#include <hip/hip_runtime.h>
#include <hip/hip_bf16.h>
#include <math.h>

#define BB 32
#define SS 1024
#define DD 1024

typedef __bf16 bf16_t;
typedef __bf16 bf16x4 __attribute__((ext_vector_type(4)));
typedef __bf16 bf16x8 __attribute__((ext_vector_type(8)));
typedef float f32x4 __attribute__((ext_vector_type(4)));

// async global -> LDS, 16B per lane. lds pointer must be wave-uniform;
// HW writes lds_base + lane*16 (linear). Swizzled layouts are achieved by
// pre-swizzling the per-lane GLOBAL source address (m173 pattern).
__device__ __forceinline__ void gload16(const void* g, void* lds_uniform) {
    __builtin_amdgcn_global_load_lds(
        (const __attribute__((address_space(1))) void*)g,
        (__attribute__((address_space(3))) void*)lds_uniform, 16, 0, 0);
}

// ---------------------------------------------------------------------------
// split fp32 -> (hi, lo) bf16.  hi = bf16(f), lo = bf16(f - hi).
// ---------------------------------------------------------------------------
__global__ __launch_bounds__(256) void split_fp32(
    const float* __restrict__ src, bf16_t* __restrict__ hi,
    bf16_t* __restrict__ lo, int n4)
{
    for (int idx = blockIdx.x * 256 + threadIdx.x; idx < n4;
         idx += gridDim.x * 256) {
        float4 f = ((const float4*)src)[idx];
        bf16x4 h, l;
        h.x = (bf16_t)f.x; h.y = (bf16_t)f.y; h.z = (bf16_t)f.z; h.w = (bf16_t)f.w;
        l.x = (bf16_t)(f.x - (float)h.x);
        l.y = (bf16_t)(f.y - (float)h.y);
        l.z = (bf16_t)(f.z - (float)h.z);
        l.w = (bf16_t)(f.w - (float)h.w);
        ((bf16x4*)hi)[idx] = h;
        ((bf16x4*)lo)[idx] = l;
    }
}

// LDS tile: [128 rows][4 chunks of 16B]. Chunk swizzle: LDS slot (row,c)
// holds global chunk c ^ ((row>>1)&3). 16 lanes of a ds_read_b128 then hit
// 8 distinct 16B slots (2-way bank conflict = free) instead of 2 (8-way).
// Write side: lane (row=tid>>2, c=tid&3) loads global chunk c^((tid>>3)&3).
// Read side:  global chunk g of row r lives at LDS chunk g^((r>>1)&3);
//             for our fragment pattern that is the per-lane constant
//             ((lane>>4) ^ ((lane>>1)&3)).

// ---------------------------------------------------------------------------
// Split-precision MFMA GEMM: C[m,n] = sum_k A[m,k]*B[n,k] (+bias), where
// A = Ah+Al, B = Bh+Bl in bf16 pairs. 3 passes: Ah*Bh + Ah*Bl + Al*Bh.
// 128x128 tile, 4 waves (2x2), each wave 4x4 frags of 16x16x32.
// 1-D grid 2048: n-tile = bid%8 (pins W-panel to one XCD's L2), m = bid/8.
// ---------------------------------------------------------------------------
__global__ __launch_bounds__(256) void gemm_proj_split(
    const bf16_t* __restrict__ Ah_g, const bf16_t* __restrict__ Al_g,
    const bf16_t* __restrict__ Bh_g, const bf16_t* __restrict__ Bl_g,
    const float* __restrict__ bias,
    bf16_t* __restrict__ out_hi, bf16_t* __restrict__ out_lo)
{
    __shared__ __align__(16) bf16_t Ash[128 * 32];
    __shared__ __align__(16) bf16_t Bsh[128 * 32];
    const int tid = threadIdx.x;
    const int lane = tid & 63, wid = tid >> 6;
    const int wr = wid >> 1, wc = wid & 1;
    const int bid = blockIdx.x;
    const int n0 = (bid & 7) * 128;        // XCD-pinned n-tile
    const int m0 = (bid >> 3) * 128;

    const int trow = tid >> 2;                              // 0..63
    const int gcol = (((tid & 3) ^ ((tid >> 3) & 3)) * 8);  // swizzled source chunk
    char* AldsW = (char*)Ash + wid * 1024;  // wave-uniform LDS base
    char* BldsW = (char*)Bsh + wid * 1024;

    f32x4 acc[4][4] = {};

    for (int pass = 0; pass < 3; ++pass) {
        const bf16_t* As = (pass < 2) ? Ah_g : Al_g;
        const bf16_t* Bs = (pass == 1) ? Bl_g : Bh_g;
        for (int k0 = 0; k0 < DD; k0 += 32) {
            __syncthreads();  // previous compute done before overwrite
            gload16(As + (size_t)(m0 + trow) * DD + k0 + gcol, AldsW);
            gload16(As + (size_t)(m0 + 64 + trow) * DD + k0 + gcol, AldsW + 4096);
            gload16(Bs + (size_t)(n0 + trow) * DD + k0 + gcol, BldsW);
            gload16(Bs + (size_t)(n0 + 64 + trow) * DD + k0 + gcol, BldsW + 4096);
            __syncthreads();  // compiler drains vmcnt before barrier

            const char* Ab = (const char*)Ash;
            const char* Bb = (const char*)Bsh;
            const int klane = (((lane >> 4) ^ ((lane >> 1) & 3))) * 16;
            const int rA = wr * 64 + (lane & 15);
            const int rB = wc * 64 + (lane & 15);
            bf16x8 af[4], bfr[4];
            #pragma unroll
            for (int i = 0; i < 4; ++i)
                af[i] = *(const bf16x8*)(Ab + (rA + i * 16) * 64 + klane);
            #pragma unroll
            for (int j = 0; j < 4; ++j)
                bfr[j] = *(const bf16x8*)(Bb + (rB + j * 16) * 64 + klane);
            #pragma unroll
            for (int i = 0; i < 4; ++i)
                #pragma unroll
                for (int j = 0; j < 4; ++j)
                    acc[i][j] = __builtin_amdgcn_mfma_f32_16x16x32_bf16(
                        af[i], bfr[j], acc[i][j], 0, 0, 0);
        }
    }

    // epilogue: C/D frag layout col=lane&15, row=(lane>>4)*4+r
    const int rbase = (lane >> 4) * 4;
    const int cbase = lane & 15;
    #pragma unroll
    for (int i = 0; i < 4; ++i) {
        #pragma unroll
        for (int j = 0; j < 4; ++j) {
            const int n = n0 + wc * 64 + j * 16 + cbase;
            const float bv = bias[n];
            #pragma unroll
            for (int r = 0; r < 4; ++r) {
                const int m = m0 + wr * 64 + i * 16 + rbase + r;
                float valf = acc[i][j][r] + bv;
                bf16_t h = (bf16_t)valf;
                out_hi[(size_t)m * DD + n] = h;
                out_lo[(size_t)m * DD + n] = (bf16_t)(valf - (float)h);
            }
        }
    }
}

// ---------------------------------------------------------------------------
// Scores GEMM (per batch): s[b,srow] += sum_t tanh(q.k) * v[t]
// Same split 3-pass MFMA body; epilogue fuses tanh, *v, 16-lane shuffle
// reduce, atomicAdd. 1-D grid 2048: t-tile = bid%8 (XCD-pinned k-panel),
// s = (bid>>3)&7, batch = bid>>6 -> all XCDs stream the same q panel (L3).
// ---------------------------------------------------------------------------
__global__ __launch_bounds__(256) void gemm_scores_split(
    const bf16_t* __restrict__ qh, const bf16_t* __restrict__ ql,
    const bf16_t* __restrict__ kh, const bf16_t* __restrict__ kl,
    const float* __restrict__ v, float* __restrict__ sbuf)
{
    __shared__ __align__(16) bf16_t Ash[128 * 32];
    __shared__ __align__(16) bf16_t Bsh[128 * 32];
    const int tid = threadIdx.x;
    const int lane = tid & 63, wid = tid >> 6;
    const int wr = wid >> 1, wc = wid & 1;
    const int bid = blockIdx.x;
    const int t0 = (bid & 7) * 128;          // XCD-pinned t-tile
    const int s0 = ((bid >> 3) & 7) * 128;
    const int b  = bid >> 6;
    const size_t boff = (size_t)b * SS * DD;

    const int trow = tid >> 2;
    const int gcol = (((tid & 3) ^ ((tid >> 3) & 3)) * 8);
    char* AldsW = (char*)Ash + wid * 1024;
    char* BldsW = (char*)Bsh + wid * 1024;

    f32x4 acc[4][4] = {};

    for (int pass = 0; pass < 3; ++pass) {
        const bf16_t* As = ((pass < 2) ? qh : ql) + boff;
        const bf16_t* Bs = ((pass == 1) ? kl : kh) + boff;
        for (int k0 = 0; k0 < DD; k0 += 32) {
            __syncthreads();
            gload16(As + (size_t)(s0 + trow) * DD + k0 + gcol, AldsW);
            gload16(As + (size_t)(s0 + 64 + trow) * DD + k0 + gcol, AldsW + 4096);
            gload16(Bs + (size_t)(t0 + trow) * DD + k0 + gcol, BldsW);
            gload16(Bs + (size_t)(t0 + 64 + trow) * DD + k0 + gcol, BldsW + 4096);
            __syncthreads();

            const char* Ab = (const char*)Ash;
            const char* Bb = (const char*)Bsh;
            const int klane = (((lane >> 4) ^ ((lane >> 1) & 3))) * 16;
            const int rA = wr * 64 + (lane & 15);
            const int rB = wc * 64 + (lane & 15);
            bf16x8 af[4], bfr[4];
            #pragma unroll
            for (int i = 0; i < 4; ++i)
                af[i] = *(const bf16x8*)(Ab + (rA + i * 16) * 64 + klane);
            #pragma unroll
            for (int j = 0; j < 4; ++j)
                bfr[j] = *(const bf16x8*)(Bb + (rB + j * 16) * 64 + klane);
            #pragma unroll
            for (int i = 0; i < 4; ++i)
                #pragma unroll
                for (int j = 0; j < 4; ++j)
                    acc[i][j] = __builtin_amdgcn_mfma_f32_16x16x32_bf16(
                        af[i], bfr[j], acc[i][j], 0, 0, 0);
        }
    }

    // epilogue: per output row, sum_j tanh(score)*v[t]; reduce across the
    // 16 column-lanes (xor 1,2,4,8 stays within the group; lane>>4 invariant)
    const int rbase = (lane >> 4) * 4;
    const int cbase = lane & 15;
    #pragma unroll
    for (int i = 0; i < 4; ++i) {
        #pragma unroll
        for (int r = 0; r < 4; ++r) {
            float p = 0.f;
            #pragma unroll
            for (int j = 0; j < 4; ++j) {
                const int t = t0 + wc * 64 + j * 16 + cbase;
                p += tanhf(acc[i][j][r]) * v[t];
            }
            p += __shfl_xor(p, 1);
            p += __shfl_xor(p, 2);
            p += __shfl_xor(p, 4);
            p += __shfl_xor(p, 8);
            if (cbase == 0) {
                const int srow = s0 + wr * 64 + i * 16 + rbase + r;
                atomicAdd(&sbuf[b * SS + srow], p);
            }
        }
    }
}

// ---------------------------------------------------------------------------
// softmax over S per batch
// ---------------------------------------------------------------------------
__global__ __launch_bounds__(256) void softmax_rows(
    const float* __restrict__ sbuf, float* __restrict__ wbuf)
{
    const int b = blockIdx.x, tid = threadIdx.x;
    const int wave = tid >> 6, lane = tid & 63;
    __shared__ float redm[4];
    __shared__ float redsum[4];

    float vals[4];
    float mx = -1e30f;
    #pragma unroll
    for (int i = 0; i < 4; ++i) {
        vals[i] = sbuf[b * SS + i * 256 + tid];
        mx = fmaxf(mx, vals[i]);
    }
    #pragma unroll
    for (int off = 32; off; off >>= 1) mx = fmaxf(mx, __shfl_xor(mx, off));
    if (lane == 0) redm[wave] = mx;
    __syncthreads();
    mx = fmaxf(fmaxf(redm[0], redm[1]), fmaxf(redm[2], redm[3]));

    float sum = 0.f;
    #pragma unroll
    for (int i = 0; i < 4; ++i) { vals[i] = expf(vals[i] - mx); sum += vals[i]; }
    #pragma unroll
    for (int off = 32; off; off >>= 1) sum += __shfl_xor(sum, off);
    if (lane == 0) redsum[wave] = sum;
    __syncthreads();
    sum = redsum[0] + redsum[1] + redsum[2] + redsum[3];

    float inv = 1.0f / sum;
    #pragma unroll
    for (int i = 0; i < 4; ++i) wbuf[b * SS + i * 256 + tid] = vals[i] * inv;
}

// ---------------------------------------------------------------------------
// out[b,d] = sum_s w[b,s] * x[b,s,d]
// ---------------------------------------------------------------------------
__global__ __launch_bounds__(256) void weighted_sum(
    const float* __restrict__ x, const float* __restrict__ wbuf,
    float* __restrict__ out)
{
    __shared__ float wl[SS];
    const int b = blockIdx.y;
    const int d = blockIdx.x * 256 + threadIdx.x;
    for (int i = threadIdx.x; i < SS; i += 256) wl[i] = wbuf[b * SS + i];
    __syncthreads();

    const float* xb = x + (size_t)b * SS * DD + d;
    float acc = 0.f;
    for (int s = 0; s < SS; ++s) acc += wl[s] * xb[(size_t)s * DD];
    out[b * DD + d] = acc;
}

// ======================= round-1 fp32 fallback kernels ======================
__global__ __launch_bounds__(256) void linear_qk(
    const float* __restrict__ x, const float* __restrict__ W,
    const float* __restrict__ bias, float* __restrict__ y)
{
    __shared__ float As[16][68];
    __shared__ float Ws[16][68];
    const int tid = threadIdx.x;
    const int tx = tid & 15, ty = tid >> 4;
    const int m0 = blockIdx.y * 64;
    const int n0 = blockIdx.x * 64;
    float acc[4][4] = {};
    for (int k0 = 0; k0 < DD; k0 += 16) {
        #pragma unroll
        for (int i = 0; i < 4; ++i) {
            int idx = i * 256 + tid;
            int kk = idx & 15, mm = idx >> 4;
            As[kk][mm] = x[(size_t)(m0 + mm) * DD + (k0 + kk)];
            Ws[kk][mm] = W[(size_t)(n0 + mm) * DD + (k0 + kk)];
        }
        __syncthreads();
        #pragma unroll
        for (int kk = 0; kk < 16; ++kk) {
            float4 a = *(const float4*)&As[kk][ty * 4];
            float4 w = *(const float4*)&Ws[kk][tx * 4];
            acc[0][0] += a.x * w.x; acc[0][1] += a.x * w.y; acc[0][2] += a.x * w.z; acc[0][3] += a.x * w.w;
            acc[1][0] += a.y * w.x; acc[1][1] += a.y * w.y; acc[1][2] += a.y * w.z; acc[1][3] += a.y * w.w;
            acc[2][0] += a.z * w.x; acc[2][1] += a.z * w.y; acc[2][2] += a.z * w.z; acc[2][3] += a.z * w.w;
            acc[3][0] += a.w * w.x; acc[3][1] += a.w * w.y; acc[3][2] += a.w * w.z; acc[3][3] += a.w * w.w;
        }
        __syncthreads();
    }
    #pragma unroll
    for (int i = 0; i < 4; ++i) {
        int m = m0 + ty * 4 + i;
        #pragma unroll
        for (int j = 0; j < 4; ++j) {
            int n = n0 + tx * 4 + j;
            y[(size_t)m * DD + n] = acc[i][j] + bias[n];
        }
    }
}

__global__ __launch_bounds__(256) void scores_reduce(
    const float* __restrict__ q, const float* __restrict__ k,
    const float* __restrict__ v, float* __restrict__ s_out)
{
    __shared__ float As[16][68];
    __shared__ float Ws[16][68];
    __shared__ float red[64][17];
    const int tid = threadIdx.x;
    const int tx = tid & 15, ty = tid >> 4;
    const int b  = blockIdx.z;
    const int s0 = blockIdx.y * 64;
    const int t0 = blockIdx.x * 64;
    const float* qb = q + (size_t)b * SS * DD;
    const float* kb = k + (size_t)b * SS * DD;
    float acc[4][4] = {};
    for (int k0 = 0; k0 < DD; k0 += 16) {
        #pragma unroll
        for (int i = 0; i < 4; ++i) {
            int idx = i * 256 + tid;
            int kk = idx & 15, mm = idx >> 4;
            As[kk][mm] = qb[(size_t)(s0 + mm) * DD + (k0 + kk)];
            Ws[kk][mm] = kb[(size_t)(t0 + mm) * DD + (k0 + kk)];
        }
        __syncthreads();
        #pragma unroll
        for (int kk = 0; kk < 16; ++kk) {
            float4 a = *(const float4*)&As[kk][ty * 4];
            float4 w = *(const float4*)&Ws[kk][tx * 4];
            acc[0][0] += a.x * w.x; acc[0][1] += a.x * w.y; acc[0][2] += a.x * w.z; acc[0][3] += a.x * w.w;
            acc[1][0] += a.y * w.x; acc[1][1] += a.y * w.y; acc[1][2] += a.y * w.z; acc[1][3] += a.y * w.w;
            acc[2][0] += a.z * w.x; acc[2][1] += a.z * w.y; acc[2][2] += a.z * w.z; acc[2][3] += a.z * w.w;
            acc[3][0] += a.w * w.x; acc[3][1] += a.w * w.y; acc[3][2] += a.w * w.z; acc[3][3] += a.w * w.w;
        }
        __syncthreads();
    }
    float vj[4];
    #pragma unroll
    for (int j = 0; j < 4; ++j) vj[j] = v[t0 + tx * 4 + j];
    #pragma unroll
    for (int i = 0; i < 4; ++i) {
        float p = 0.f;
        #pragma unroll
        for (int j = 0; j < 4; ++j) p += tanhf(acc[i][j]) * vj[j];
        red[ty * 4 + i][tx] = p;
    }
    __syncthreads();
    if (tid < 64) {
        float tot = 0.f;
        #pragma unroll
        for (int c = 0; c < 16; ++c) tot += red[tid][c];
        atomicAdd(&s_out[b * SS + s0 + tid], tot);
    }
}

// ---------------------------------------------------------------------------
extern "C" void kernel_launch(void* const* d_in, const int* in_sizes, int n_in,
                              void* d_out, int out_size, void* d_ws, size_t ws_size,
                              hipStream_t stream) {
    const float* x  = (const float*)d_in[0];
    const float* Wq = (const float*)d_in[1];
    const float* bq = (const float*)d_in[2];
    const float* Wk = (const float*)d_in[3];
    const float* bk = (const float*)d_in[4];
    const float* v  = (const float*)d_in[5];
    float* out = (float*)d_out;

    const size_t nx = (size_t)BB * SS * DD;   // 33,554,432
    const size_t nw = (size_t)DD * DD;        // 1,048,576
    const size_t need = nx * 2 * 6 + nw * 2 * 4 + (size_t)BB * SS * 4 * 2;

    dim3 blk(256);

    if (ws_size >= need) {
        // ---- fast path: split-precision bf16 MFMA ----
        char* p = (char*)d_ws;
        bf16_t* xh  = (bf16_t*)p;            p += nx * 2;
        bf16_t* xl  = (bf16_t*)p;            p += nx * 2;
        bf16_t* qh  = (bf16_t*)p;            p += nx * 2;
        bf16_t* ql  = (bf16_t*)p;            p += nx * 2;
        bf16_t* kh  = (bf16_t*)p;            p += nx * 2;
        bf16_t* kl  = (bf16_t*)p;            p += nx * 2;
        bf16_t* wqh = (bf16_t*)p;            p += nw * 2;
        bf16_t* wql = (bf16_t*)p;            p += nw * 2;
        bf16_t* wkh = (bf16_t*)p;            p += nw * 2;
        bf16_t* wkl = (bf16_t*)p;            p += nw * 2;
        float*  sbuf = (float*)p;            p += (size_t)BB * SS * 4;
        float*  wbuf = (float*)p;

        hipMemsetAsync(sbuf, 0, (size_t)BB * SS * sizeof(float), stream);

        split_fp32<<<2048, blk, 0, stream>>>(x,  xh,  xl,  (int)(nx / 4));
        split_fp32<<<512,  blk, 0, stream>>>(Wq, wqh, wql, (int)(nw / 4));
        split_fp32<<<512,  blk, 0, stream>>>(Wk, wkh, wkl, (int)(nw / 4));

        // 1-D grids, XCD = bid%8 pinning (see kernel comments)
        gemm_proj_split<<<2048, blk, 0, stream>>>(xh, xl, wqh, wql, bq, qh, ql);
        gemm_proj_split<<<2048, blk, 0, stream>>>(xh, xl, wkh, wkl, bk, kh, kl);

        gemm_scores_split<<<2048, blk, 0, stream>>>(qh, ql, kh, kl, v, sbuf);

        softmax_rows<<<BB, blk, 0, stream>>>(sbuf, wbuf);
        dim3 g4(DD / 256, BB);
        weighted_sum<<<g4, blk, 0, stream>>>(x, wbuf, out);
    } else {
        // ---- fallback: round-1 fp32 path ----
        float* q    = (float*)d_ws;
        float* kk   = q + nx;
        float* sbuf = kk + nx;
        float* wbuf = sbuf + BB * SS;

        hipMemsetAsync(sbuf, 0, (size_t)BB * SS * sizeof(float), stream);

        dim3 g1(DD / 64, (BB * SS) / 64);
        linear_qk<<<g1, blk, 0, stream>>>(x, Wq, bq, q);
        linear_qk<<<g1, blk, 0, stream>>>(x, Wk, bk, kk);
        dim3 g2(SS / 64, SS / 64, BB);
        scores_reduce<<<g2, blk, 0, stream>>>(q, kk, v, sbuf);
        softmax_rows<<<BB, blk, 0, stream>>>(sbuf, wbuf);
        dim3 g4(DD / 256, BB);
        weighted_sum<<<g4, blk, 0, stream>>>(x, wbuf, out);
    }
}

// Round 4
// 843.862 us; speedup vs baseline: 3.5251x; 1.2728x over previous
//
#include <hip/hip_runtime.h>
#include <hip/hip_bf16.h>
#include <math.h>

#define BB 32
#define SS 1024
#define DD 1024

typedef __bf16 bf16_t;
typedef __bf16 bf16x4 __attribute__((ext_vector_type(4)));
typedef __bf16 bf16x8 __attribute__((ext_vector_type(8)));
typedef float f32x4 __attribute__((ext_vector_type(4)));

// async global -> LDS, 16B per lane. LDS pointer must be wave-uniform;
// HW writes lds_base + lane*16 (linear). Swizzled LDS layouts are achieved
// by pre-swizzling the per-lane GLOBAL source address (m173 pattern).
__device__ __forceinline__ void gload16(const void* g, void* lds_uniform) {
    __builtin_amdgcn_global_load_lds(
        (const __attribute__((address_space(1))) void*)g,
        (__attribute__((address_space(3))) void*)lds_uniform, 16, 0, 0);
}

// ---------------------------------------------------------------------------
// split fp32 -> (hi, lo) bf16.  hi = bf16(f), lo = bf16(f - hi).
// ---------------------------------------------------------------------------
__global__ __launch_bounds__(256) void split_fp32(
    const float* __restrict__ src, bf16_t* __restrict__ hi,
    bf16_t* __restrict__ lo, int n4)
{
    for (int idx = blockIdx.x * 256 + threadIdx.x; idx < n4;
         idx += gridDim.x * 256) {
        float4 f = ((const float4*)src)[idx];
        bf16x4 h, l;
        h.x = (bf16_t)f.x; h.y = (bf16_t)f.y; h.z = (bf16_t)f.z; h.w = (bf16_t)f.w;
        l.x = (bf16_t)(f.x - (float)h.x);
        l.y = (bf16_t)(f.y - (float)h.y);
        l.z = (bf16_t)(f.z - (float)h.z);
        l.w = (bf16_t)(f.w - (float)h.w);
        ((bf16x4*)hi)[idx] = h;
        ((bf16x4*)lo)[idx] = l;
    }
}

// ---------------------------------------------------------------------------
// split x -> hi/lo AND compute per-row alpha = x_row . avec, beta = x_row . bvec
// Each 256-thread block iteration covers exactly one row (1024 floats), so
// alpha/beta rows are written exactly once (plain stores). MUST be launched
// with grid = 2048 so 2048*256*4 divides B*S*D.
// ---------------------------------------------------------------------------
__global__ __launch_bounds__(256) void split_x_ab(
    const float* __restrict__ src, bf16_t* __restrict__ hi,
    bf16_t* __restrict__ lo, const float* __restrict__ avec,
    const float* __restrict__ bvec, float* __restrict__ alpha,
    float* __restrict__ beta)
{
    __shared__ float reda[4], redb[4];
    const int tid = threadIdx.x;
    const int lane = tid & 63, wave = tid >> 6;
    const float4 av = ((const float4*)avec)[tid];   // d = tid*4 .. tid*4+3
    const float4 bv = ((const float4*)bvec)[tid];
    const int n4 = BB * SS * DD / 4;
    for (int idx = blockIdx.x * 256 + tid; idx < n4; idx += gridDim.x * 256) {
        float4 f = ((const float4*)src)[idx];
        bf16x4 h, l;
        h.x = (bf16_t)f.x; h.y = (bf16_t)f.y; h.z = (bf16_t)f.z; h.w = (bf16_t)f.w;
        l.x = (bf16_t)(f.x - (float)h.x);
        l.y = (bf16_t)(f.y - (float)h.y);
        l.z = (bf16_t)(f.z - (float)h.z);
        l.w = (bf16_t)(f.w - (float)h.w);
        ((bf16x4*)hi)[idx] = h;
        ((bf16x4*)lo)[idx] = l;

        float pa = f.x * av.x + f.y * av.y + f.z * av.z + f.w * av.w;
        float pb = f.x * bv.x + f.y * bv.y + f.z * bv.z + f.w * bv.w;
        #pragma unroll
        for (int off = 32; off; off >>= 1) {
            pa += __shfl_xor(pa, off);
            pb += __shfl_xor(pb, off);
        }
        if (lane == 0) { reda[wave] = pa; redb[wave] = pb; }
        __syncthreads();
        if (tid == 0) {
            const int row = idx >> 8;   // 256 float4 per row
            alpha[row] = reda[0] + reda[1] + reda[2] + reda[3];
            beta[row]  = redb[0] + redb[1] + redb[2] + redb[3];
        }
        __syncthreads();
    }
}

// ---------------------------------------------------------------------------
// avec[d] = sum_e Wq[e,d]*bk[e] (z=0), bvec[d] = sum_e Wk[e,d]*bq[e] (z=1).
// grid (4, 16, 2); avec/bvec must be zeroed first (atomicAdd partials).
// ---------------------------------------------------------------------------
__global__ __launch_bounds__(256) void bias_gemv(
    const float* __restrict__ Wq, const float* __restrict__ Wk,
    const float* __restrict__ bq, const float* __restrict__ bk,
    float* __restrict__ avec, float* __restrict__ bvec)
{
    const float* W   = blockIdx.z ? Wk : Wq;
    const float* bb  = blockIdx.z ? bq : bk;
    float* outv      = blockIdx.z ? bvec : avec;
    const int d  = blockIdx.x * 256 + threadIdx.x;
    const int e0 = blockIdx.y * 64;
    float s = 0.f;
    for (int e = e0; e < e0 + 64; ++e) s += W[(size_t)e * DD + d] * bb[e];
    atomicAdd(&outv[d], s);
}

__global__ __launch_bounds__(256) void dot_c(
    const float* __restrict__ bq, const float* __restrict__ bk,
    float* __restrict__ cbuf)
{
    __shared__ float red[4];
    const int tid = threadIdx.x, lane = tid & 63, wave = tid >> 6;
    float s = 0.f;
    for (int e = tid; e < DD; e += 256) s += bq[e] * bk[e];
    #pragma unroll
    for (int off = 32; off; off >>= 1) s += __shfl_xor(s, off);
    if (lane == 0) red[wave] = s;
    __syncthreads();
    if (tid == 0) cbuf[0] = red[0] + red[1] + red[2] + red[3];
}

// ---------------------------------------------------------------------------
// Mt[n,k] = sum_e Wk[e,n] * Wq[e,k]   (row-major [n][k]; Mt = (Wq^T Wk)^T)
// fp32 VALU, 64x64 tile; all global loads are coalesced rows.
// ---------------------------------------------------------------------------
__global__ __launch_bounds__(256) void mt_f32(
    const float* __restrict__ Wk, const float* __restrict__ Wq,
    float* __restrict__ Mt)
{
    __shared__ float Us[16][68];
    __shared__ float Vs[16][68];
    const int tid = threadIdx.x;
    const int tx = tid & 15, ty = tid >> 4;
    const int i0 = blockIdx.y * 64;   // n
    const int j0 = blockIdx.x * 64;   // k
    float acc[4][4] = {};
    for (int e0 = 0; e0 < DD; e0 += 16) {
        #pragma unroll
        for (int r = 0; r < 4; ++r) {
            const int kk = (tid >> 6) + r * 4;
            const int cc = tid & 63;
            Us[kk][cc] = Wk[(size_t)(e0 + kk) * DD + i0 + cc];
            Vs[kk][cc] = Wq[(size_t)(e0 + kk) * DD + j0 + cc];
        }
        __syncthreads();
        #pragma unroll
        for (int kk = 0; kk < 16; ++kk) {
            float4 a = *(const float4*)&Us[kk][ty * 4];
            float4 w = *(const float4*)&Vs[kk][tx * 4];
            acc[0][0] += a.x * w.x; acc[0][1] += a.x * w.y; acc[0][2] += a.x * w.z; acc[0][3] += a.x * w.w;
            acc[1][0] += a.y * w.x; acc[1][1] += a.y * w.y; acc[1][2] += a.y * w.z; acc[1][3] += a.y * w.w;
            acc[2][0] += a.z * w.x; acc[2][1] += a.z * w.y; acc[2][2] += a.z * w.z; acc[2][3] += a.z * w.w;
            acc[3][0] += a.w * w.x; acc[3][1] += a.w * w.y; acc[3][2] += a.w * w.z; acc[3][3] += a.w * w.w;
        }
        __syncthreads();
    }
    #pragma unroll
    for (int i = 0; i < 4; ++i)
        #pragma unroll
        for (int j = 0; j < 4; ++j)
            Mt[(size_t)(i0 + ty * 4 + i) * DD + j0 + tx * 4 + j] = acc[i][j];
}

// LDS chunk swizzle (round-3, verified 0 conflicts): LDS slot (row,c) holds
// global chunk c ^ ((row>>1)&3). Write side pre-swizzles the global source;
// read side uses per-lane constant klane = ((lane>>4) ^ ((lane>>1)&3))*16.

// Double-buffered staging of one 128x32 bf16 tile pair for step u
// (u in [0,96): pass = u>>5 selects hi/lo operands, k0 = (u&31)*32).
#define STAGE_AB(buf, u, Ah_, Al_, Bh_, Bl_, r0A, r0B)                        \
    do {                                                                      \
        const int p_  = (u) >> 5;                                             \
        const int k0_ = ((u) & 31) * 32;                                      \
        const bf16_t* As_ = (p_ == 2) ? (Al_) : (Ah_);                        \
        const bf16_t* Bs_ = (p_ == 1) ? (Bl_) : (Bh_);                        \
        char* Ad_ = (char*)Ash[buf] + wid * 1024;                             \
        char* Bd_ = (char*)Bsh[buf] + wid * 1024;                             \
        gload16(As_ + (size_t)((r0A) + trow) * DD + k0_ + gcol, Ad_);         \
        gload16(As_ + (size_t)((r0A) + 64 + trow) * DD + k0_ + gcol, Ad_ + 4096); \
        gload16(Bs_ + (size_t)((r0B) + trow) * DD + k0_ + gcol, Bd_);         \
        gload16(Bs_ + (size_t)((r0B) + 64 + trow) * DD + k0_ + gcol, Bd_ + 4096); \
    } while (0)

// ---------------------------------------------------------------------------
// Split-precision MFMA GEMM: C[m,n] = sum_k A[m,k]*B[n,k] (+optional bias),
// A = Ah+Al, B = Bh+Bl bf16 pairs, 3 passes (AhBh, AhBl, AlBh).
// 128x128 tile, 4 waves, 16x16x32 MFMA, double-buffered LDS (one barrier
// per K-step; next-step global_load_lds overlaps current-step MFMA).
// Epilogue writes hi/lo bf16 split of the fp32 result.
// ---------------------------------------------------------------------------
__global__ __launch_bounds__(256) void gemm_AB_split(
    const bf16_t* __restrict__ Ah_g, const bf16_t* __restrict__ Al_g,
    const bf16_t* __restrict__ Bh_g, const bf16_t* __restrict__ Bl_g,
    const float* __restrict__ bias,
    bf16_t* __restrict__ out_hi, bf16_t* __restrict__ out_lo)
{
    __shared__ __align__(16) bf16_t Ash[2][128 * 32];
    __shared__ __align__(16) bf16_t Bsh[2][128 * 32];
    const int tid = threadIdx.x;
    const int lane = tid & 63, wid = tid >> 6;
    const int wr = wid >> 1, wc = wid & 1;
    const int bid = blockIdx.x;
    const int n0 = (bid & 7) * 128;        // XCD-pinned n-tile (B panel in L2)
    const int m0 = (bid >> 3) * 128;

    const int trow = tid >> 2;
    const int gcol = ((tid & 3) ^ ((tid >> 3) & 3)) * 8;
    const int klane = ((lane >> 4) ^ ((lane >> 1) & 3)) * 16;
    const int rA = wr * 64 + (lane & 15);
    const int rB = wc * 64 + (lane & 15);

    f32x4 acc[4][4] = {};

    STAGE_AB(0, 0, Ah_g, Al_g, Bh_g, Bl_g, m0, n0);
    int cur = 0;
    for (int u = 0; u < 96; ++u) {
        __syncthreads();   // implicit vmcnt(0): buf[cur] staged; all reads of buf[cur^1] done
        if (u + 1 < 96)
            STAGE_AB(cur ^ 1, u + 1, Ah_g, Al_g, Bh_g, Bl_g, m0, n0);
        const char* Ab = (const char*)Ash[cur];
        const char* Bb = (const char*)Bsh[cur];
        bf16x8 af[4], bfr[4];
        #pragma unroll
        for (int i = 0; i < 4; ++i)
            af[i] = *(const bf16x8*)(Ab + (rA + i * 16) * 64 + klane);
        #pragma unroll
        for (int j = 0; j < 4; ++j)
            bfr[j] = *(const bf16x8*)(Bb + (rB + j * 16) * 64 + klane);
        #pragma unroll
        for (int i = 0; i < 4; ++i)
            #pragma unroll
            for (int j = 0; j < 4; ++j)
                acc[i][j] = __builtin_amdgcn_mfma_f32_16x16x32_bf16(
                    af[i], bfr[j], acc[i][j], 0, 0, 0);
        cur ^= 1;
    }

    // epilogue: C/D frag layout col=lane&15, row=(lane>>4)*4+r
    const int rbase = (lane >> 4) * 4;
    const int cbase = lane & 15;
    #pragma unroll
    for (int i = 0; i < 4; ++i) {
        #pragma unroll
        for (int j = 0; j < 4; ++j) {
            const int n = n0 + wc * 64 + j * 16 + cbase;
            const float bv = bias ? bias[n] : 0.0f;
            #pragma unroll
            for (int r = 0; r < 4; ++r) {
                const int m = m0 + wr * 64 + i * 16 + rbase + r;
                float valf = acc[i][j][r] + bv;
                bf16_t h = (bf16_t)valf;
                out_hi[(size_t)m * DD + n] = h;
                out_lo[(size_t)m * DD + n] = (bf16_t)(valf - (float)h);
            }
        }
    }
}

// ---------------------------------------------------------------------------
// Scores GEMM (per batch): s[b,srow] += sum_t tanh(y.x + alpha_s + beta_t + c) * v[t]
// A = y splits, B = x splits. Same double-buffered body; fused epilogue.
// grid 2048: t-tile = bid&7 (XCD-pinned), s-tile = (bid>>3)&7, b = bid>>6.
// ---------------------------------------------------------------------------
__global__ __launch_bounds__(256) void gemm_scores_split(
    const bf16_t* __restrict__ yh, const bf16_t* __restrict__ yl,
    const bf16_t* __restrict__ xh, const bf16_t* __restrict__ xl,
    const float* __restrict__ v, const float* __restrict__ alpha,
    const float* __restrict__ beta, const float* __restrict__ cbuf,
    float* __restrict__ sbuf)
{
    __shared__ __align__(16) bf16_t Ash[2][128 * 32];
    __shared__ __align__(16) bf16_t Bsh[2][128 * 32];
    const int tid = threadIdx.x;
    const int lane = tid & 63, wid = tid >> 6;
    const int wr = wid >> 1, wc = wid & 1;
    const int bid = blockIdx.x;
    const int t0 = (bid & 7) * 128;
    const int s0 = ((bid >> 3) & 7) * 128;
    const int b  = bid >> 6;
    const size_t boff = (size_t)b * SS * DD;

    const bf16_t* Ah_g = yh + boff;
    const bf16_t* Al_g = yl + boff;
    const bf16_t* Bh_g = xh + boff;
    const bf16_t* Bl_g = xl + boff;

    const int trow = tid >> 2;
    const int gcol = ((tid & 3) ^ ((tid >> 3) & 3)) * 8;
    const int klane = ((lane >> 4) ^ ((lane >> 1) & 3)) * 16;
    const int rA = wr * 64 + (lane & 15);
    const int rB = wc * 64 + (lane & 15);

    f32x4 acc[4][4] = {};

    STAGE_AB(0, 0, Ah_g, Al_g, Bh_g, Bl_g, s0, t0);
    int cur = 0;
    for (int u = 0; u < 96; ++u) {
        __syncthreads();
        if (u + 1 < 96)
            STAGE_AB(cur ^ 1, u + 1, Ah_g, Al_g, Bh_g, Bl_g, s0, t0);
        const char* Ab = (const char*)Ash[cur];
        const char* Bb = (const char*)Bsh[cur];
        bf16x8 af[4], bfr[4];
        #pragma unroll
        for (int i = 0; i < 4; ++i)
            af[i] = *(const bf16x8*)(Ab + (rA + i * 16) * 64 + klane);
        #pragma unroll
        for (int j = 0; j < 4; ++j)
            bfr[j] = *(const bf16x8*)(Bb + (rB + j * 16) * 64 + klane);
        #pragma unroll
        for (int i = 0; i < 4; ++i)
            #pragma unroll
            for (int j = 0; j < 4; ++j)
                acc[i][j] = __builtin_amdgcn_mfma_f32_16x16x32_bf16(
                    af[i], bfr[j], acc[i][j], 0, 0, 0);
        cur ^= 1;
    }

    // epilogue: tanh(score + alpha_s + beta_t + c) * v[t]; reduce across the
    // 16 column-lanes (xor 1,2,4,8 stays within the group), atomicAdd per row.
    const float c0 = cbuf[0];
    const int rbase = (lane >> 4) * 4;
    const int cbase = lane & 15;
    #pragma unroll
    for (int i = 0; i < 4; ++i) {
        #pragma unroll
        for (int r = 0; r < 4; ++r) {
            const int srow = s0 + wr * 64 + i * 16 + rbase + r;
            const float al = alpha[b * SS + srow] + c0;
            float p = 0.f;
            #pragma unroll
            for (int j = 0; j < 4; ++j) {
                const int t = t0 + wc * 64 + j * 16 + cbase;
                p += tanhf(acc[i][j][r] + al + beta[b * SS + t]) * v[t];
            }
            p += __shfl_xor(p, 1);
            p += __shfl_xor(p, 2);
            p += __shfl_xor(p, 4);
            p += __shfl_xor(p, 8);
            if (cbase == 0) {
                atomicAdd(&sbuf[b * SS + srow], p);
            }
        }
    }
}

// ---------------------------------------------------------------------------
// softmax over S per batch
// ---------------------------------------------------------------------------
__global__ __launch_bounds__(256) void softmax_rows(
    const float* __restrict__ sbuf, float* __restrict__ wbuf)
{
    const int b = blockIdx.x, tid = threadIdx.x;
    const int wave = tid >> 6, lane = tid & 63;
    __shared__ float redm[4];
    __shared__ float redsum[4];

    float vals[4];
    float mx = -1e30f;
    #pragma unroll
    for (int i = 0; i < 4; ++i) {
        vals[i] = sbuf[b * SS + i * 256 + tid];
        mx = fmaxf(mx, vals[i]);
    }
    #pragma unroll
    for (int off = 32; off; off >>= 1) mx = fmaxf(mx, __shfl_xor(mx, off));
    if (lane == 0) redm[wave] = mx;
    __syncthreads();
    mx = fmaxf(fmaxf(redm[0], redm[1]), fmaxf(redm[2], redm[3]));

    float sum = 0.f;
    #pragma unroll
    for (int i = 0; i < 4; ++i) { vals[i] = expf(vals[i] - mx); sum += vals[i]; }
    #pragma unroll
    for (int off = 32; off; off >>= 1) sum += __shfl_xor(sum, off);
    if (lane == 0) redsum[wave] = sum;
    __syncthreads();
    sum = redsum[0] + redsum[1] + redsum[2] + redsum[3];

    float inv = 1.0f / sum;
    #pragma unroll
    for (int i = 0; i < 4; ++i) wbuf[b * SS + i * 256 + tid] = vals[i] * inv;
}

// ---------------------------------------------------------------------------
// out[b,d] = sum_s w[b,s] * x[b,s,d]
// ---------------------------------------------------------------------------
__global__ __launch_bounds__(256) void weighted_sum(
    const float* __restrict__ x, const float* __restrict__ wbuf,
    float* __restrict__ out)
{
    __shared__ float wl[SS];
    const int b = blockIdx.y;
    const int d = blockIdx.x * 256 + threadIdx.x;
    for (int i = threadIdx.x; i < SS; i += 256) wl[i] = wbuf[b * SS + i];
    __syncthreads();

    const float* xb = x + (size_t)b * SS * DD + d;
    float acc = 0.f;
    for (int s = 0; s < SS; ++s) acc += wl[s] * xb[(size_t)s * DD];
    out[b * DD + d] = acc;
}

// ======================= round-1 fp32 fallback kernels ======================
__global__ __launch_bounds__(256) void linear_qk(
    const float* __restrict__ x, const float* __restrict__ W,
    const float* __restrict__ bias, float* __restrict__ y)
{
    __shared__ float As[16][68];
    __shared__ float Ws[16][68];
    const int tid = threadIdx.x;
    const int tx = tid & 15, ty = tid >> 4;
    const int m0 = blockIdx.y * 64;
    const int n0 = blockIdx.x * 64;
    float acc[4][4] = {};
    for (int k0 = 0; k0 < DD; k0 += 16) {
        #pragma unroll
        for (int i = 0; i < 4; ++i) {
            int idx = i * 256 + tid;
            int kk = idx & 15, mm = idx >> 4;
            As[kk][mm] = x[(size_t)(m0 + mm) * DD + (k0 + kk)];
            Ws[kk][mm] = W[(size_t)(n0 + mm) * DD + (k0 + kk)];
        }
        __syncthreads();
        #pragma unroll
        for (int kk = 0; kk < 16; ++kk) {
            float4 a = *(const float4*)&As[kk][ty * 4];
            float4 w = *(const float4*)&Ws[kk][tx * 4];
            acc[0][0] += a.x * w.x; acc[0][1] += a.x * w.y; acc[0][2] += a.x * w.z; acc[0][3] += a.x * w.w;
            acc[1][0] += a.y * w.x; acc[1][1] += a.y * w.y; acc[1][2] += a.y * w.z; acc[1][3] += a.y * w.w;
            acc[2][0] += a.z * w.x; acc[2][1] += a.z * w.y; acc[2][2] += a.z * w.z; acc[2][3] += a.z * w.w;
            acc[3][0] += a.w * w.x; acc[3][1] += a.w * w.y; acc[3][2] += a.w * w.z; acc[3][3] += a.w * w.w;
        }
        __syncthreads();
    }
    #pragma unroll
    for (int i = 0; i < 4; ++i) {
        int m = m0 + ty * 4 + i;
        #pragma unroll
        for (int j = 0; j < 4; ++j) {
            int n = n0 + tx * 4 + j;
            y[(size_t)m * DD + n] = acc[i][j] + bias[n];
        }
    }
}

__global__ __launch_bounds__(256) void scores_reduce(
    const float* __restrict__ q, const float* __restrict__ k,
    const float* __restrict__ v, float* __restrict__ s_out)
{
    __shared__ float As[16][68];
    __shared__ float Ws[16][68];
    __shared__ float red[64][17];
    const int tid = threadIdx.x;
    const int tx = tid & 15, ty = tid >> 4;
    const int b  = blockIdx.z;
    const int s0 = blockIdx.y * 64;
    const int t0 = blockIdx.x * 64;
    const float* qb = q + (size_t)b * SS * DD;
    const float* kb = k + (size_t)b * SS * DD;
    float acc[4][4] = {};
    for (int k0 = 0; k0 < DD; k0 += 16) {
        #pragma unroll
        for (int i = 0; i < 4; ++i) {
            int idx = i * 256 + tid;
            int kk = idx & 15, mm = idx >> 4;
            As[kk][mm] = qb[(size_t)(s0 + mm) * DD + (k0 + kk)];
            Ws[kk][mm] = kb[(size_t)(t0 + mm) * DD + (k0 + kk)];
        }
        __syncthreads();
        #pragma unroll
        for (int kk = 0; kk < 16; ++kk) {
            float4 a = *(const float4*)&As[kk][ty * 4];
            float4 w = *(const float4*)&Ws[kk][tx * 4];
            acc[0][0] += a.x * w.x; acc[0][1] += a.x * w.y; acc[0][2] += a.x * w.z; acc[0][3] += a.x * w.w;
            acc[1][0] += a.y * w.x; acc[1][1] += a.y * w.y; acc[1][2] += a.y * w.z; acc[1][3] += a.y * w.w;
            acc[2][0] += a.z * w.x; acc[2][1] += a.z * w.y; acc[2][2] += a.z * w.z; acc[2][3] += a.z * w.w;
            acc[3][0] += a.w * w.x; acc[3][1] += a.w * w.y; acc[3][2] += a.w * w.z; acc[3][3] += a.w * w.w;
        }
        __syncthreads();
    }
    float vj[4];
    #pragma unroll
    for (int j = 0; j < 4; ++j) vj[j] = v[t0 + tx * 4 + j];
    #pragma unroll
    for (int i = 0; i < 4; ++i) {
        float p = 0.f;
        #pragma unroll
        for (int j = 0; j < 4; ++j) p += tanhf(acc[i][j]) * vj[j];
        red[ty * 4 + i][tx] = p;
    }
    __syncthreads();
    if (tid < 64) {
        float tot = 0.f;
        #pragma unroll
        for (int c = 0; c < 16; ++c) tot += red[tid][c];
        atomicAdd(&s_out[b * SS + s0 + tid], tot);
    }
}

// ---------------------------------------------------------------------------
extern "C" void kernel_launch(void* const* d_in, const int* in_sizes, int n_in,
                              void* d_out, int out_size, void* d_ws, size_t ws_size,
                              hipStream_t stream) {
    const float* x  = (const float*)d_in[0];
    const float* Wq = (const float*)d_in[1];
    const float* bq = (const float*)d_in[2];
    const float* Wk = (const float*)d_in[3];
    const float* bk = (const float*)d_in[4];
    const float* v  = (const float*)d_in[5];
    float* out = (float*)d_out;

    const size_t nx = (size_t)BB * SS * DD;   // 33,554,432
    const size_t nw = (size_t)DD * DD;        // 1,048,576
    // xh,xl,yh,yl (bf16) + Mt (f32) + Mth,Mtl (bf16) + avec,bvec,cbuf +
    // alpha,beta,sbuf,wbuf
    const size_t need = nx * 2 * 4 + nw * 4 + nw * 2 * 2 +
                        4096 * 2 + 16 + (size_t)BB * SS * 4 * 4;

    dim3 blk(256);

    if (ws_size >= need) {
        // ---- fast path: M = Wq^T Wk factorization + split-bf16 MFMA ----
        char* p = (char*)d_ws;
        bf16_t* xh  = (bf16_t*)p;   p += nx * 2;
        bf16_t* xl  = (bf16_t*)p;   p += nx * 2;
        bf16_t* yh  = (bf16_t*)p;   p += nx * 2;
        bf16_t* yl  = (bf16_t*)p;   p += nx * 2;
        float*  Mt  = (float*)p;    p += nw * 4;
        bf16_t* Mth = (bf16_t*)p;   p += nw * 2;
        bf16_t* Mtl = (bf16_t*)p;   p += nw * 2;
        float*  avec = (float*)p;   p += 4096;
        float*  bvec = (float*)p;   p += 4096;
        float*  cbuf = (float*)p;   p += 16;
        float*  alpha = (float*)p;  p += (size_t)BB * SS * 4;
        float*  beta  = (float*)p;  p += (size_t)BB * SS * 4;
        float*  sbuf  = (float*)p;  p += (size_t)BB * SS * 4;
        float*  wbuf  = (float*)p;

        hipMemsetAsync(sbuf, 0, (size_t)BB * SS * sizeof(float), stream);
        hipMemsetAsync(avec, 0, 4096 * 2, stream);   // avec + bvec

        bias_gemv<<<dim3(4, 16, 2), blk, 0, stream>>>(Wq, Wk, bq, bk, avec, bvec);
        dot_c<<<1, blk, 0, stream>>>(bq, bk, cbuf);
        split_x_ab<<<2048, blk, 0, stream>>>(x, xh, xl, avec, bvec, alpha, beta);
        mt_f32<<<dim3(16, 16), blk, 0, stream>>>(Wk, Wq, Mt);
        split_fp32<<<512, blk, 0, stream>>>(Mt, Mth, Mtl, (int)(nw / 4));

        // y = x * M   (B operand = Mt[n,k] = M[k,n])
        gemm_AB_split<<<2048, blk, 0, stream>>>(xh, xl, Mth, Mtl, nullptr, yh, yl);
        // scores = y * x^T fused with tanh, *v, row-reduce
        gemm_scores_split<<<2048, blk, 0, stream>>>(yh, yl, xh, xl, v,
                                                    alpha, beta, cbuf, sbuf);

        softmax_rows<<<BB, blk, 0, stream>>>(sbuf, wbuf);
        dim3 g4(DD / 256, BB);
        weighted_sum<<<g4, blk, 0, stream>>>(x, wbuf, out);
    } else {
        // ---- fallback: round-1 fp32 path ----
        float* q    = (float*)d_ws;
        float* kk   = q + nx;
        float* sbuf = kk + nx;
        float* wbuf = sbuf + BB * SS;

        hipMemsetAsync(sbuf, 0, (size_t)BB * SS * sizeof(float), stream);

        dim3 g1(DD / 64, (BB * SS) / 64);
        linear_qk<<<g1, blk, 0, stream>>>(x, Wq, bq, q);
        linear_qk<<<g1, blk, 0, stream>>>(x, Wk, bk, kk);
        dim3 g2(SS / 64, SS / 64, BB);
        scores_reduce<<<g2, blk, 0, stream>>>(q, kk, v, sbuf);
        softmax_rows<<<BB, blk, 0, stream>>>(sbuf, wbuf);
        dim3 g4(DD / 256, BB);
        weighted_sum<<<g4, blk, 0, stream>>>(x, wbuf, out);
    }
}

// Round 5
// 743.378 us; speedup vs baseline: 4.0016x; 1.1352x over previous
//
#include <hip/hip_runtime.h>
#include <hip/hip_bf16.h>
#include <math.h>

#define BB 32
#define SS 1024
#define DD 1024
#define NT 48      // K-tiles: 3 split passes x (1024/64)
#define NITER 24   // NT/2

typedef __bf16 bf16_t;
typedef __bf16 bf16x4 __attribute__((ext_vector_type(4)));
typedef __bf16 bf16x8 __attribute__((ext_vector_type(8)));
typedef float f32x4 __attribute__((ext_vector_type(4)));

// async global -> LDS, 16B per lane. LDS pointer must be wave-uniform;
// HW writes lds_base + lane*16 (linear). Swizzled LDS layouts are achieved
// by pre-swizzling the per-lane GLOBAL source address (m173 pattern).
__device__ __forceinline__ void gload16(const void* g, void* lds_uniform) {
    __builtin_amdgcn_global_load_lds(
        (const __attribute__((address_space(1))) void*)g,
        (__attribute__((address_space(3))) void*)lds_uniform, 16, 0, 0);
}

// ---------------------------------------------------------------------------
// 256x64 bf16 K-tile staging, 512 threads, 4 x global_load_lds (8KB each).
// LDS layout: row-major [256][128B]; chunk swizzle: LDS slot (row, c) holds
// global chunk c ^ (row & 7)  (chunks are 16B). Thread t -> LDS offset t*16
// within each 8KB block (linear), so source chunk = (t&7) ^ ((t>>3)&7).
// ---------------------------------------------------------------------------
__device__ __forceinline__ void stage_tile(const bf16_t* __restrict__ src,
                                           int row0, int k0, char* ldsTile,
                                           int tid) {
    const int rr = tid >> 3;                       // 0..63 row within 8KB block
    const int cc = ((tid & 7) ^ (rr & 7)) * 8;     // swizzled source chunk
    char* d = ldsTile + (tid >> 6) * 1024;         // wave-uniform dest
    const bf16_t* s = src + (size_t)(row0 + rr) * DD + k0 + cc;
    #pragma unroll
    for (int j = 0; j < 4; ++j)
        gload16(s + (size_t)j * 64 * DD, d + j * 8192);
}

// fragment read: rows row0..row0+15 (lane&15), k-slice ks (0/1), chunk
// g = ks*4 + (lane>>4), swizzled by row&7. row0 is a multiple of 16 so
// row&7 == lane&7.
__device__ __forceinline__ bf16x8 rdfrag(const char* tile, int row0, int ks,
                                         int lane) {
    const int r = row0 + (lane & 15);
    const int g = ks * 4 + (lane >> 4);
    return *(const bf16x8*)(tile + r * 128 + ((g ^ (r & 7)) * 16));
}

// one phase: quadrant (qr,qc) of the wave's 128x64 output, K=64 (one K-tile)
__device__ __forceinline__ void qphase(const bf16_t* Abuf, const bf16_t* Bbuf,
                                       int qr, int qc, int wm, int wn, int lane,
                                       f32x4 acc[8][4]) {
    bf16x8 af[4][2], bg[2][2];
    #pragma unroll
    for (int ii = 0; ii < 4; ++ii)
        #pragma unroll
        for (int ks = 0; ks < 2; ++ks)
            af[ii][ks] = rdfrag((const char*)Abuf,
                                wm * 128 + qr * 64 + ii * 16, ks, lane);
    #pragma unroll
    for (int jj = 0; jj < 2; ++jj)
        #pragma unroll
        for (int ks = 0; ks < 2; ++ks)
            bg[jj][ks] = rdfrag((const char*)Bbuf,
                                wn * 64 + qc * 32 + jj * 16, ks, lane);
    __builtin_amdgcn_s_barrier();
    asm volatile("s_waitcnt lgkmcnt(0)" ::: "memory");
    __builtin_amdgcn_s_setprio(1);
    #pragma unroll
    for (int ii = 0; ii < 4; ++ii)
        #pragma unroll
        for (int jj = 0; jj < 2; ++jj)
            #pragma unroll
            for (int ks = 0; ks < 2; ++ks)
                acc[qr * 4 + ii][qc * 2 + jj] =
                    __builtin_amdgcn_mfma_f32_16x16x32_bf16(
                        af[ii][ks], bg[jj][ks],
                        acc[qr * 4 + ii][qc * 2 + jj], 0, 0, 0);
    __builtin_amdgcn_s_setprio(0);
    __builtin_amdgcn_s_barrier();
}

// ---------------------------------------------------------------------------
// 8-phase K-loop over 48 K-tiles (3 split-precision passes x 16).
// K-tile u lives in buf[u&1]: phases 0-3 read buf0 (K-tile 2i), 4-7 read
// buf1 (K-tile 2i+1). Staging: phases 0/1 stage A/B of K-tile 2i+1 -> buf1,
// phases 4/5 stage A/B of K-tile 2i+2 -> buf0. A wave's vmcnt(0) sits just
// BEFORE the barrier ending phases 3 and 7: own-loads-landed + barrier =>
// whole buffer valid for all waves' reads in the next phase group.
// ---------------------------------------------------------------------------
__device__ __forceinline__ void kloop256(
    const bf16_t* __restrict__ Ahi, const bf16_t* __restrict__ Alo,
    const bf16_t* __restrict__ Bhi, const bf16_t* __restrict__ Blo,
    int rowA, int rowB, int tid, int lane, int wm, int wn,
    bf16_t (*Asm)[256 * 64], bf16_t (*Bsm)[256 * 64], f32x4 acc[8][4]) {
    // pass selection: A uses lo only in pass 2; B uses lo only in pass 1
#define SEL_A(u) ((((u) >> 4) == 2) ? Alo : Ahi)
#define SEL_B(u) ((((u) >> 4) == 1) ? Blo : Bhi)
#define K0OF(u) (((u) & 15) * 64)

    // prologue: K-tile 0 -> buf0
    stage_tile(SEL_A(0), rowA, 0, (char*)Asm[0], tid);
    stage_tile(SEL_B(0), rowB, 0, (char*)Bsm[0], tid);
    asm volatile("s_waitcnt vmcnt(0)" ::: "memory");
    __builtin_amdgcn_s_barrier();

    for (int it = 0; it < NITER; ++it) {
        const int u1 = 2 * it + 1, u2 = 2 * it + 2;
        const bool st = (it < NITER - 1);
        // phase 0: stage A(u1)->buf1, compute q(0,0) on buf0
        stage_tile(SEL_A(u1), rowA, K0OF(u1), (char*)Asm[1], tid);
        qphase(Asm[0], Bsm[0], 0, 0, wm, wn, lane, acc);
        // phase 1: stage B(u1)->buf1
        stage_tile(SEL_B(u1), rowB, K0OF(u1), (char*)Bsm[1], tid);
        qphase(Asm[0], Bsm[0], 0, 1, wm, wn, lane, acc);
        // phase 2
        qphase(Asm[0], Bsm[0], 1, 0, wm, wn, lane, acc);
        // phase 3: publish buf1 (vmcnt before its closing barrier)
        {
            bf16x8 af[4][2], bg[2][2];
            #pragma unroll
            for (int ii = 0; ii < 4; ++ii)
                #pragma unroll
                for (int ks = 0; ks < 2; ++ks)
                    af[ii][ks] = rdfrag((const char*)Asm[0],
                                        wm * 128 + 64 + ii * 16, ks, lane);
            #pragma unroll
            for (int jj = 0; jj < 2; ++jj)
                #pragma unroll
                for (int ks = 0; ks < 2; ++ks)
                    bg[jj][ks] = rdfrag((const char*)Bsm[0],
                                        wn * 64 + 32 + jj * 16, ks, lane);
            __builtin_amdgcn_s_barrier();
            asm volatile("s_waitcnt lgkmcnt(0)" ::: "memory");
            __builtin_amdgcn_s_setprio(1);
            #pragma unroll
            for (int ii = 0; ii < 4; ++ii)
                #pragma unroll
                for (int jj = 0; jj < 2; ++jj)
                    #pragma unroll
                    for (int ks = 0; ks < 2; ++ks)
                        acc[4 + ii][2 + jj] =
                            __builtin_amdgcn_mfma_f32_16x16x32_bf16(
                                af[ii][ks], bg[jj][ks], acc[4 + ii][2 + jj],
                                0, 0, 0);
            __builtin_amdgcn_s_setprio(0);
            asm volatile("s_waitcnt vmcnt(0)" ::: "memory");  // u1 landed
            __builtin_amdgcn_s_barrier();                     // buf1 published
        }
        // phase 4: stage A(u2)->buf0 (all buf0 reads done), compute on buf1
        if (st) stage_tile(SEL_A(u2), rowA, K0OF(u2), (char*)Asm[0], tid);
        qphase(Asm[1], Bsm[1], 0, 0, wm, wn, lane, acc);
        // phase 5: stage B(u2)->buf0
        if (st) stage_tile(SEL_B(u2), rowB, K0OF(u2), (char*)Bsm[0], tid);
        qphase(Asm[1], Bsm[1], 0, 1, wm, wn, lane, acc);
        // phase 6
        qphase(Asm[1], Bsm[1], 1, 0, wm, wn, lane, acc);
        // phase 7: publish buf0
        {
            bf16x8 af[4][2], bg[2][2];
            #pragma unroll
            for (int ii = 0; ii < 4; ++ii)
                #pragma unroll
                for (int ks = 0; ks < 2; ++ks)
                    af[ii][ks] = rdfrag((const char*)Asm[1],
                                        wm * 128 + 64 + ii * 16, ks, lane);
            #pragma unroll
            for (int jj = 0; jj < 2; ++jj)
                #pragma unroll
                for (int ks = 0; ks < 2; ++ks)
                    bg[jj][ks] = rdfrag((const char*)Bsm[1],
                                        wn * 64 + 32 + jj * 16, ks, lane);
            __builtin_amdgcn_s_barrier();
            asm volatile("s_waitcnt lgkmcnt(0)" ::: "memory");
            __builtin_amdgcn_s_setprio(1);
            #pragma unroll
            for (int ii = 0; ii < 4; ++ii)
                #pragma unroll
                for (int jj = 0; jj < 2; ++jj)
                    #pragma unroll
                    for (int ks = 0; ks < 2; ++ks)
                        acc[4 + ii][2 + jj] =
                            __builtin_amdgcn_mfma_f32_16x16x32_bf16(
                                af[ii][ks], bg[jj][ks], acc[4 + ii][2 + jj],
                                0, 0, 0);
            __builtin_amdgcn_s_setprio(0);
            asm volatile("s_waitcnt vmcnt(0)" ::: "memory");  // u2 landed
            __builtin_amdgcn_s_barrier();                     // buf0 published
        }
    }
#undef SEL_A
#undef SEL_B
#undef K0OF
}

// ---------------------------------------------------------------------------
// y = x * M  (B operand = Mt[n,k] = M[k,n]); split-precision 3-pass via
// the flattened 48-K-tile loop. Writes hi/lo bf16 split of fp32 result.
// grid 512 (1-D, XCD-swizzled): m-tile = lin>>2 (128), n-tile = lin&3 (4).
// ---------------------------------------------------------------------------
__global__ __launch_bounds__(512, 2) void gemm_y_256(
    const bf16_t* __restrict__ xh, const bf16_t* __restrict__ xl,
    const bf16_t* __restrict__ Mth, const bf16_t* __restrict__ Mtl,
    bf16_t* __restrict__ out_hi, bf16_t* __restrict__ out_lo)
{
    __shared__ __align__(16) bf16_t Asm[2][256 * 64];
    __shared__ __align__(16) bf16_t Bsm[2][256 * 64];
    const int tid = threadIdx.x;
    const int lane = tid & 63, wid = tid >> 6;
    const int wm = wid >> 2, wn = wid & 3;
    const int lin = (blockIdx.x & 7) * 64 + (blockIdx.x >> 3);
    const int m0 = (lin >> 2) * 256;
    const int n0 = (lin & 3) * 256;

    f32x4 acc[8][4] = {};
    kloop256(xh, xl, Mth, Mtl, m0, n0, tid, lane, wm, wn, Asm, Bsm, acc);

    // epilogue: C/D frag layout col=lane&15, row=(lane>>4)*4+r
    const int rbase = (lane >> 4) * 4;
    const int cbase = lane & 15;
    #pragma unroll
    for (int fr = 0; fr < 8; ++fr) {
        #pragma unroll
        for (int fc = 0; fc < 4; ++fc) {
            const int n = n0 + wn * 64 + fc * 16 + cbase;
            #pragma unroll
            for (int r = 0; r < 4; ++r) {
                const int m = m0 + wm * 128 + fr * 16 + rbase + r;
                float vf = acc[fr][fc][r];
                bf16_t h = (bf16_t)vf;
                out_hi[(size_t)m * DD + n] = h;
                out_lo[(size_t)m * DD + n] = (bf16_t)(vf - (float)h);
            }
        }
    }
}

// ---------------------------------------------------------------------------
// Scores (per batch): s[b,srow] += sum_t tanh(y.x + alpha_s + beta_t + c)*v[t]
// grid 512 (XCD-swizzled): t-tile = lin&3, s-tile = (lin>>2)&3, b = lin>>4.
// ---------------------------------------------------------------------------
__global__ __launch_bounds__(512, 2) void gemm_scores_256(
    const bf16_t* __restrict__ yh, const bf16_t* __restrict__ yl,
    const bf16_t* __restrict__ xh, const bf16_t* __restrict__ xl,
    const float* __restrict__ v, const float* __restrict__ alpha,
    const float* __restrict__ beta, const float* __restrict__ cbuf,
    float* __restrict__ sbuf)
{
    __shared__ __align__(16) bf16_t Asm[2][256 * 64];
    __shared__ __align__(16) bf16_t Bsm[2][256 * 64];
    const int tid = threadIdx.x;
    const int lane = tid & 63, wid = tid >> 6;
    const int wm = wid >> 2, wn = wid & 3;
    const int lin = (blockIdx.x & 7) * 64 + (blockIdx.x >> 3);
    const int t0 = (lin & 3) * 256;
    const int s0 = ((lin >> 2) & 3) * 256;
    const int b  = lin >> 4;
    const size_t boff = (size_t)b * SS * DD;

    f32x4 acc[8][4] = {};
    kloop256(yh + boff, yl + boff, xh + boff, xl + boff, s0, t0,
             tid, lane, wm, wn, Asm, Bsm, acc);

    // epilogue: tanh(score + alpha_s + beta_t + c)*v[t]; 16-lane col reduce.
    const float c0 = cbuf[0];
    const int rbase = (lane >> 4) * 4;
    const int cbase = lane & 15;
    float bet[4], vv[4];
    #pragma unroll
    for (int fc = 0; fc < 4; ++fc) {
        const int t = t0 + wn * 64 + fc * 16 + cbase;
        bet[fc] = beta[b * SS + t];
        vv[fc]  = v[t];
    }
    #pragma unroll
    for (int fr = 0; fr < 8; ++fr) {
        #pragma unroll
        for (int r = 0; r < 4; ++r) {
            const int srow = s0 + wm * 128 + fr * 16 + rbase + r;
            const float al = alpha[b * SS + srow] + c0;
            float p = 0.f;
            #pragma unroll
            for (int fc = 0; fc < 4; ++fc)
                p += tanhf(acc[fr][fc][r] + al + bet[fc]) * vv[fc];
            p += __shfl_xor(p, 1);
            p += __shfl_xor(p, 2);
            p += __shfl_xor(p, 4);
            p += __shfl_xor(p, 8);
            if (cbase == 0) atomicAdd(&sbuf[b * SS + srow], p);
        }
    }
}

// ---------------------------------------------------------------------------
// split fp32 -> (hi, lo) bf16.  hi = bf16(f), lo = bf16(f - hi).
// ---------------------------------------------------------------------------
__global__ __launch_bounds__(256) void split_fp32(
    const float* __restrict__ src, bf16_t* __restrict__ hi,
    bf16_t* __restrict__ lo, int n4)
{
    for (int idx = blockIdx.x * 256 + threadIdx.x; idx < n4;
         idx += gridDim.x * 256) {
        float4 f = ((const float4*)src)[idx];
        bf16x4 h, l;
        h.x = (bf16_t)f.x; h.y = (bf16_t)f.y; h.z = (bf16_t)f.z; h.w = (bf16_t)f.w;
        l.x = (bf16_t)(f.x - (float)h.x);
        l.y = (bf16_t)(f.y - (float)h.y);
        l.z = (bf16_t)(f.z - (float)h.z);
        l.w = (bf16_t)(f.w - (float)h.w);
        ((bf16x4*)hi)[idx] = h;
        ((bf16x4*)lo)[idx] = l;
    }
}

// ---------------------------------------------------------------------------
// split x -> hi/lo AND per-row alpha = x_row.avec, beta = x_row.bvec.
// Launch with grid = 2048 exactly (one row per block-iteration).
// ---------------------------------------------------------------------------
__global__ __launch_bounds__(256) void split_x_ab(
    const float* __restrict__ src, bf16_t* __restrict__ hi,
    bf16_t* __restrict__ lo, const float* __restrict__ avec,
    const float* __restrict__ bvec, float* __restrict__ alpha,
    float* __restrict__ beta)
{
    __shared__ float reda[4], redb[4];
    const int tid = threadIdx.x;
    const int lane = tid & 63, wave = tid >> 6;
    const float4 av = ((const float4*)avec)[tid];
    const float4 bv = ((const float4*)bvec)[tid];
    const int n4 = BB * SS * DD / 4;
    for (int idx = blockIdx.x * 256 + tid; idx < n4; idx += gridDim.x * 256) {
        float4 f = ((const float4*)src)[idx];
        bf16x4 h, l;
        h.x = (bf16_t)f.x; h.y = (bf16_t)f.y; h.z = (bf16_t)f.z; h.w = (bf16_t)f.w;
        l.x = (bf16_t)(f.x - (float)h.x);
        l.y = (bf16_t)(f.y - (float)h.y);
        l.z = (bf16_t)(f.z - (float)h.z);
        l.w = (bf16_t)(f.w - (float)h.w);
        ((bf16x4*)hi)[idx] = h;
        ((bf16x4*)lo)[idx] = l;

        float pa = f.x * av.x + f.y * av.y + f.z * av.z + f.w * av.w;
        float pb = f.x * bv.x + f.y * bv.y + f.z * bv.z + f.w * bv.w;
        #pragma unroll
        for (int off = 32; off; off >>= 1) {
            pa += __shfl_xor(pa, off);
            pb += __shfl_xor(pb, off);
        }
        if (lane == 0) { reda[wave] = pa; redb[wave] = pb; }
        __syncthreads();
        if (tid == 0) {
            const int row = idx >> 8;
            alpha[row] = reda[0] + reda[1] + reda[2] + reda[3];
            beta[row]  = redb[0] + redb[1] + redb[2] + redb[3];
        }
        __syncthreads();
    }
}

// ---------------------------------------------------------------------------
// avec[d] = sum_e Wq[e,d]*bk[e] (z=0), bvec[d] = sum_e Wk[e,d]*bq[e] (z=1).
// ---------------------------------------------------------------------------
__global__ __launch_bounds__(256) void bias_gemv(
    const float* __restrict__ Wq, const float* __restrict__ Wk,
    const float* __restrict__ bq, const float* __restrict__ bk,
    float* __restrict__ avec, float* __restrict__ bvec)
{
    const float* W   = blockIdx.z ? Wk : Wq;
    const float* bb  = blockIdx.z ? bq : bk;
    float* outv      = blockIdx.z ? bvec : avec;
    const int d  = blockIdx.x * 256 + threadIdx.x;
    const int e0 = blockIdx.y * 64;
    float s = 0.f;
    for (int e = e0; e < e0 + 64; ++e) s += W[(size_t)e * DD + d] * bb[e];
    atomicAdd(&outv[d], s);
}

__global__ __launch_bounds__(256) void dot_c(
    const float* __restrict__ bq, const float* __restrict__ bk,
    float* __restrict__ cbuf)
{
    __shared__ float red[4];
    const int tid = threadIdx.x, lane = tid & 63, wave = tid >> 6;
    float s = 0.f;
    for (int e = tid; e < DD; e += 256) s += bq[e] * bk[e];
    #pragma unroll
    for (int off = 32; off; off >>= 1) s += __shfl_xor(s, off);
    if (lane == 0) red[wave] = s;
    __syncthreads();
    if (tid == 0) cbuf[0] = red[0] + red[1] + red[2] + red[3];
}

// ---------------------------------------------------------------------------
// Mt[n,k] = sum_e Wk[e,n] * Wq[e,k]   (fp32 VALU, 64x64 tile)
// ---------------------------------------------------------------------------
__global__ __launch_bounds__(256) void mt_f32(
    const float* __restrict__ Wk, const float* __restrict__ Wq,
    float* __restrict__ Mt)
{
    __shared__ float Us[16][68];
    __shared__ float Vs[16][68];
    const int tid = threadIdx.x;
    const int tx = tid & 15, ty = tid >> 4;
    const int i0 = blockIdx.y * 64;
    const int j0 = blockIdx.x * 64;
    float acc[4][4] = {};
    for (int e0 = 0; e0 < DD; e0 += 16) {
        #pragma unroll
        for (int r = 0; r < 4; ++r) {
            const int kk = (tid >> 6) + r * 4;
            const int cc = tid & 63;
            Us[kk][cc] = Wk[(size_t)(e0 + kk) * DD + i0 + cc];
            Vs[kk][cc] = Wq[(size_t)(e0 + kk) * DD + j0 + cc];
        }
        __syncthreads();
        #pragma unroll
        for (int kk = 0; kk < 16; ++kk) {
            float4 a = *(const float4*)&Us[kk][ty * 4];
            float4 w = *(const float4*)&Vs[kk][tx * 4];
            acc[0][0] += a.x * w.x; acc[0][1] += a.x * w.y; acc[0][2] += a.x * w.z; acc[0][3] += a.x * w.w;
            acc[1][0] += a.y * w.x; acc[1][1] += a.y * w.y; acc[1][2] += a.y * w.z; acc[1][3] += a.y * w.w;
            acc[2][0] += a.z * w.x; acc[2][1] += a.z * w.y; acc[2][2] += a.z * w.z; acc[2][3] += a.z * w.w;
            acc[3][0] += a.w * w.x; acc[3][1] += a.w * w.y; acc[3][2] += a.w * w.z; acc[3][3] += a.w * w.w;
        }
        __syncthreads();
    }
    #pragma unroll
    for (int i = 0; i < 4; ++i)
        #pragma unroll
        for (int j = 0; j < 4; ++j)
            Mt[(size_t)(i0 + ty * 4 + i) * DD + j0 + tx * 4 + j] = acc[i][j];
}

// ---------------------------------------------------------------------------
// softmax over S per batch
// ---------------------------------------------------------------------------
__global__ __launch_bounds__(256) void softmax_rows(
    const float* __restrict__ sbuf, float* __restrict__ wbuf)
{
    const int b = blockIdx.x, tid = threadIdx.x;
    const int wave = tid >> 6, lane = tid & 63;
    __shared__ float redm[4];
    __shared__ float redsum[4];

    float vals[4];
    float mx = -1e30f;
    #pragma unroll
    for (int i = 0; i < 4; ++i) {
        vals[i] = sbuf[b * SS + i * 256 + tid];
        mx = fmaxf(mx, vals[i]);
    }
    #pragma unroll
    for (int off = 32; off; off >>= 1) mx = fmaxf(mx, __shfl_xor(mx, off));
    if (lane == 0) redm[wave] = mx;
    __syncthreads();
    mx = fmaxf(fmaxf(redm[0], redm[1]), fmaxf(redm[2], redm[3]));

    float sum = 0.f;
    #pragma unroll
    for (int i = 0; i < 4; ++i) { vals[i] = expf(vals[i] - mx); sum += vals[i]; }
    #pragma unroll
    for (int off = 32; off; off >>= 1) sum += __shfl_xor(sum, off);
    if (lane == 0) redsum[wave] = sum;
    __syncthreads();
    sum = redsum[0] + redsum[1] + redsum[2] + redsum[3];

    float inv = 1.0f / sum;
    #pragma unroll
    for (int i = 0; i < 4; ++i) wbuf[b * SS + i * 256 + tid] = vals[i] * inv;
}

// ---------------------------------------------------------------------------
// out[b,d] = sum_s w[b,s] * x[b,s,d]
// ---------------------------------------------------------------------------
__global__ __launch_bounds__(256) void weighted_sum(
    const float* __restrict__ x, const float* __restrict__ wbuf,
    float* __restrict__ out)
{
    __shared__ float wl[SS];
    const int b = blockIdx.y;
    const int d = blockIdx.x * 256 + threadIdx.x;
    for (int i = threadIdx.x; i < SS; i += 256) wl[i] = wbuf[b * SS + i];
    __syncthreads();

    const float* xb = x + (size_t)b * SS * DD + d;
    float acc = 0.f;
    for (int s = 0; s < SS; ++s) acc += wl[s] * xb[(size_t)s * DD];
    out[b * DD + d] = acc;
}

// ======================= round-1 fp32 fallback kernels ======================
__global__ __launch_bounds__(256) void linear_qk(
    const float* __restrict__ x, const float* __restrict__ W,
    const float* __restrict__ bias, float* __restrict__ y)
{
    __shared__ float As[16][68];
    __shared__ float Ws[16][68];
    const int tid = threadIdx.x;
    const int tx = tid & 15, ty = tid >> 4;
    const int m0 = blockIdx.y * 64;
    const int n0 = blockIdx.x * 64;
    float acc[4][4] = {};
    for (int k0 = 0; k0 < DD; k0 += 16) {
        #pragma unroll
        for (int i = 0; i < 4; ++i) {
            int idx = i * 256 + tid;
            int kk = idx & 15, mm = idx >> 4;
            As[kk][mm] = x[(size_t)(m0 + mm) * DD + (k0 + kk)];
            Ws[kk][mm] = W[(size_t)(n0 + mm) * DD + (k0 + kk)];
        }
        __syncthreads();
        #pragma unroll
        for (int kk = 0; kk < 16; ++kk) {
            float4 a = *(const float4*)&As[kk][ty * 4];
            float4 w = *(const float4*)&Ws[kk][tx * 4];
            acc[0][0] += a.x * w.x; acc[0][1] += a.x * w.y; acc[0][2] += a.x * w.z; acc[0][3] += a.x * w.w;
            acc[1][0] += a.y * w.x; acc[1][1] += a.y * w.y; acc[1][2] += a.y * w.z; acc[1][3] += a.y * w.w;
            acc[2][0] += a.z * w.x; acc[2][1] += a.z * w.y; acc[2][2] += a.z * w.z; acc[2][3] += a.z * w.w;
            acc[3][0] += a.w * w.x; acc[3][1] += a.w * w.y; acc[3][2] += a.w * w.z; acc[3][3] += a.w * w.w;
        }
        __syncthreads();
    }
    #pragma unroll
    for (int i = 0; i < 4; ++i) {
        int m = m0 + ty * 4 + i;
        #pragma unroll
        for (int j = 0; j < 4; ++j) {
            int n = n0 + tx * 4 + j;
            y[(size_t)m * DD + n] = acc[i][j] + bias[n];
        }
    }
}

__global__ __launch_bounds__(256) void scores_reduce(
    const float* __restrict__ q, const float* __restrict__ k,
    const float* __restrict__ v, float* __restrict__ s_out)
{
    __shared__ float As[16][68];
    __shared__ float Ws[16][68];
    __shared__ float red[64][17];
    const int tid = threadIdx.x;
    const int tx = tid & 15, ty = tid >> 4;
    const int b  = blockIdx.z;
    const int s0 = blockIdx.y * 64;
    const int t0 = blockIdx.x * 64;
    const float* qb = q + (size_t)b * SS * DD;
    const float* kb = k + (size_t)b * SS * DD;
    float acc[4][4] = {};
    for (int k0 = 0; k0 < DD; k0 += 16) {
        #pragma unroll
        for (int i = 0; i < 4; ++i) {
            int idx = i * 256 + tid;
            int kk = idx & 15, mm = idx >> 4;
            As[kk][mm] = qb[(size_t)(s0 + mm) * DD + (k0 + kk)];
            Ws[kk][mm] = kb[(size_t)(t0 + mm) * DD + (k0 + kk)];
        }
        __syncthreads();
        #pragma unroll
        for (int kk = 0; kk < 16; ++kk) {
            float4 a = *(const float4*)&As[kk][ty * 4];
            float4 w = *(const float4*)&Ws[kk][tx * 4];
            acc[0][0] += a.x * w.x; acc[0][1] += a.x * w.y; acc[0][2] += a.x * w.z; acc[0][3] += a.x * w.w;
            acc[1][0] += a.y * w.x; acc[1][1] += a.y * w.y; acc[1][2] += a.y * w.z; acc[1][3] += a.y * w.w;
            acc[2][0] += a.z * w.x; acc[2][1] += a.z * w.y; acc[2][2] += a.z * w.z; acc[2][3] += a.z * w.w;
            acc[3][0] += a.w * w.x; acc[3][1] += a.w * w.y; acc[3][2] += a.w * w.z; acc[3][3] += a.w * w.w;
        }
        __syncthreads();
    }
    float vj[4];
    #pragma unroll
    for (int j = 0; j < 4; ++j) vj[j] = v[t0 + tx * 4 + j];
    #pragma unroll
    for (int i = 0; i < 4; ++i) {
        float p = 0.f;
        #pragma unroll
        for (int j = 0; j < 4; ++j) p += tanhf(acc[i][j]) * vj[j];
        red[ty * 4 + i][tx] = p;
    }
    __syncthreads();
    if (tid < 64) {
        float tot = 0.f;
        #pragma unroll
        for (int c = 0; c < 16; ++c) tot += red[tid][c];
        atomicAdd(&s_out[b * SS + s0 + tid], tot);
    }
}

// ---------------------------------------------------------------------------
extern "C" void kernel_launch(void* const* d_in, const int* in_sizes, int n_in,
                              void* d_out, int out_size, void* d_ws, size_t ws_size,
                              hipStream_t stream) {
    const float* x  = (const float*)d_in[0];
    const float* Wq = (const float*)d_in[1];
    const float* bq = (const float*)d_in[2];
    const float* Wk = (const float*)d_in[3];
    const float* bk = (const float*)d_in[4];
    const float* v  = (const float*)d_in[5];
    float* out = (float*)d_out;

    const size_t nx = (size_t)BB * SS * DD;   // 33,554,432
    const size_t nw = (size_t)DD * DD;        // 1,048,576
    const size_t need = nx * 2 * 4 + nw * 4 + nw * 2 * 2 +
                        4096 * 2 + 16 + (size_t)BB * SS * 4 * 4;

    dim3 blk(256);

    if (ws_size >= need) {
        // ---- fast path: M = Wq^T Wk factorization + 8-phase split GEMMs ----
        char* p = (char*)d_ws;
        bf16_t* xh  = (bf16_t*)p;   p += nx * 2;
        bf16_t* xl  = (bf16_t*)p;   p += nx * 2;
        bf16_t* yh  = (bf16_t*)p;   p += nx * 2;
        bf16_t* yl  = (bf16_t*)p;   p += nx * 2;
        float*  Mt  = (float*)p;    p += nw * 4;
        bf16_t* Mth = (bf16_t*)p;   p += nw * 2;
        bf16_t* Mtl = (bf16_t*)p;   p += nw * 2;
        float*  avec = (float*)p;   p += 4096;
        float*  bvec = (float*)p;   p += 4096;
        float*  cbuf = (float*)p;   p += 16;
        float*  alpha = (float*)p;  p += (size_t)BB * SS * 4;
        float*  beta  = (float*)p;  p += (size_t)BB * SS * 4;
        float*  sbuf  = (float*)p;  p += (size_t)BB * SS * 4;
        float*  wbuf  = (float*)p;

        hipMemsetAsync(sbuf, 0, (size_t)BB * SS * sizeof(float), stream);
        hipMemsetAsync(avec, 0, 4096 * 2, stream);

        bias_gemv<<<dim3(4, 16, 2), blk, 0, stream>>>(Wq, Wk, bq, bk, avec, bvec);
        dot_c<<<1, blk, 0, stream>>>(bq, bk, cbuf);
        split_x_ab<<<2048, blk, 0, stream>>>(x, xh, xl, avec, bvec, alpha, beta);
        mt_f32<<<dim3(16, 16), blk, 0, stream>>>(Wk, Wq, Mt);
        split_fp32<<<512, blk, 0, stream>>>(Mt, Mth, Mtl, (int)(nw / 4));

        gemm_y_256<<<512, dim3(512), 0, stream>>>(xh, xl, Mth, Mtl, yh, yl);
        gemm_scores_256<<<512, dim3(512), 0, stream>>>(yh, yl, xh, xl, v,
                                                       alpha, beta, cbuf, sbuf);

        softmax_rows<<<BB, blk, 0, stream>>>(sbuf, wbuf);
        dim3 g4(DD / 256, BB);
        weighted_sum<<<g4, blk, 0, stream>>>(x, wbuf, out);
    } else {
        // ---- fallback: round-1 fp32 path ----
        float* q    = (float*)d_ws;
        float* kk   = q + nx;
        float* sbuf = kk + nx;
        float* wbuf = sbuf + BB * SS;

        hipMemsetAsync(sbuf, 0, (size_t)BB * SS * sizeof(float), stream);

        dim3 g1(DD / 64, (BB * SS) / 64);
        linear_qk<<<g1, blk, 0, stream>>>(x, Wq, bq, q);
        linear_qk<<<g1, blk, 0, stream>>>(x, Wk, bk, kk);
        dim3 g2(SS / 64, SS / 64, BB);
        scores_reduce<<<g2, blk, 0, stream>>>(q, kk, v, sbuf);
        softmax_rows<<<BB, blk, 0, stream>>>(sbuf, wbuf);
        dim3 g4(DD / 256, BB);
        weighted_sum<<<g4, blk, 0, stream>>>(x, wbuf, out);
    }
}

// Round 6
// 704.020 us; speedup vs baseline: 4.2253x; 1.0559x over previous
//
#include <hip/hip_runtime.h>
#include <hip/hip_bf16.h>
#include <math.h>

#define BB 32
#define SS 1024
#define DD 1024
#define NT 48      // K-tiles: 3 split passes x (1024/64)
#define NITER 24   // NT/2

typedef __bf16 bf16_t;
typedef __bf16 bf16x4 __attribute__((ext_vector_type(4)));
typedef __bf16 bf16x8 __attribute__((ext_vector_type(8)));
typedef float f32x4 __attribute__((ext_vector_type(4)));

// async global -> LDS, 16B per lane. LDS pointer must be wave-uniform;
// HW writes lds_base + lane*16 (linear). Swizzled LDS layouts are achieved
// by pre-swizzling the per-lane GLOBAL source address (m173 pattern).
__device__ __forceinline__ void gload16(const void* g, void* lds_uniform) {
    __builtin_amdgcn_global_load_lds(
        (const __attribute__((address_space(1))) void*)g,
        (__attribute__((address_space(3))) void*)lds_uniform, 16, 0, 0);
}

// ---------------------------------------------------------------------------
// 256x64 bf16 K-tile staging, 512 threads, 4 x global_load_lds (8KB each).
// LDS layout: row-major [256][128B]; chunk swizzle: LDS slot (row, c) holds
// global chunk c ^ (row & 7)  (chunks are 16B). Thread t -> LDS offset t*16
// within each 8KB block (linear), so source chunk = (t&7) ^ ((t>>3)&7).
// ---------------------------------------------------------------------------
__device__ __forceinline__ void stage_tile(const bf16_t* __restrict__ src,
                                           int row0, int k0, char* ldsTile,
                                           int tid) {
    const int rr = tid >> 3;                       // 0..63 row within 8KB block
    const int cc = ((tid & 7) ^ (rr & 7)) * 8;     // swizzled source chunk
    char* d = ldsTile + (tid >> 6) * 1024;         // wave-uniform dest
    const bf16_t* s = src + (size_t)(row0 + rr) * DD + k0 + cc;
    #pragma unroll
    for (int j = 0; j < 4; ++j)
        gload16(s + (size_t)j * 64 * DD, d + j * 8192);
}

// ---------------------------------------------------------------------------
// One compute half: read 8 A-frags (h fixed) from per-lane base pointers,
// barrier-align, then 32 MFMA against register-resident B-frags.
// All ds_read addresses are base + compile-time offset (VALU-free).
// ---------------------------------------------------------------------------
__device__ __forceinline__ void mfma_half(
    const char* Ak0, const char* Ak1, const bf16x8 b0[4], const bf16x8 b1[4],
    f32x4 (*accH)[4])
{
    bf16x8 a0[4], a1[4];
    #pragma unroll
    for (int ii = 0; ii < 4; ++ii) {
        a0[ii] = *(const bf16x8*)(Ak0 + ii * 2048);
        a1[ii] = *(const bf16x8*)(Ak1 + ii * 2048);
    }
    __builtin_amdgcn_s_barrier();
    asm volatile("s_waitcnt lgkmcnt(0)" ::: "memory");
    __builtin_amdgcn_s_setprio(1);
    #pragma unroll
    for (int ii = 0; ii < 4; ++ii)
        #pragma unroll
        for (int fc = 0; fc < 4; ++fc) {
            accH[ii][fc] = __builtin_amdgcn_mfma_f32_16x16x32_bf16(
                a0[ii], b0[fc], accH[ii][fc], 0, 0, 0);
            accH[ii][fc] = __builtin_amdgcn_mfma_f32_16x16x32_bf16(
                a1[ii], b1[fc], accH[ii][fc], 0, 0, 0);
        }
    __builtin_amdgcn_s_setprio(0);
}

// ---------------------------------------------------------------------------
// One K-tile (K=64): 2 phases.
//  alpha: issue next-tile A+B staging (8 gloads), read 8 B-frags + 8 A-frags
//         (h=0), barrier, 32 MFMA.
//  beta:  read 8 A-frags (h=1), reuse B-frags from regs, 32 MFMA,
//         vmcnt(0) (own 8 loads landed), publish barrier.
// Buffer discipline: reads hit bufR; staging writes bufW (= other buffer,
// whose reads completed before the previous publish barrier).
// ---------------------------------------------------------------------------
__device__ __forceinline__ void tile_step(
    const char* ArK0, const char* ArK1, const char* BrK0, const char* BrK1,
    char* AW, char* BW, const bf16_t* srcA, const bf16_t* srcB, int k0n,
    int rowA, int rowB, int tid, bool st, f32x4 (*acc)[4])
{
    if (st) {
        stage_tile(srcA, rowA, k0n, AW, tid);
        stage_tile(srcB, rowB, k0n, BW, tid);
    }
    bf16x8 b0[4], b1[4];
    #pragma unroll
    for (int fc = 0; fc < 4; ++fc) {
        b0[fc] = *(const bf16x8*)(BrK0 + fc * 2048);
        b1[fc] = *(const bf16x8*)(BrK1 + fc * 2048);
    }
    mfma_half(ArK0, ArK1, b0, b1, acc);
    __builtin_amdgcn_s_barrier();
    mfma_half(ArK0 + 8192, ArK1 + 8192, b0, b1, acc + 4);
    if (st) asm volatile("s_waitcnt vmcnt(0)" ::: "memory");
    __builtin_amdgcn_s_barrier();
}

// ---------------------------------------------------------------------------
// K-loop over 48 K-tiles (3 split-precision passes x 16), double-buffered,
// unrolled x2 so buffer selection is static (no runtime-indexed arrays).
// ---------------------------------------------------------------------------
__device__ __forceinline__ void kloop256(
    const bf16_t* __restrict__ Ahi, const bf16_t* __restrict__ Alo,
    const bf16_t* __restrict__ Bhi, const bf16_t* __restrict__ Blo,
    int rowA, int rowB, int tid, int lane, int wm, int wn,
    bf16_t* Asm0, bf16_t* Asm1, bf16_t* Bsm0, bf16_t* Bsm1, f32x4 (*acc)[4])
{
#define SEL_A(u) ((((u) >> 4) == 2) ? Alo : Ahi)
#define SEL_B(u) ((((u) >> 4) == 1) ? Blo : Bhi)
#define K0OF(u) (((u) & 15) * 64)
    // per-lane read bases: row = (lane&15), chunk g = ks*4 + (lane>>4),
    // swizzled by row&7 (= lane&7 since row0 is a multiple of 16).
    const int lrow = (lane & 15) * 128;
    const int sw0 = ((lane >> 4) ^ (lane & 7)) * 16;
    const int sw1 = ((4 + (lane >> 4)) ^ (lane & 7)) * 16;
    const char* A0k0 = (const char*)Asm0 + wm * 16384 + lrow + sw0;
    const char* A0k1 = (const char*)Asm0 + wm * 16384 + lrow + sw1;
    const char* A1k0 = (const char*)Asm1 + wm * 16384 + lrow + sw0;
    const char* A1k1 = (const char*)Asm1 + wm * 16384 + lrow + sw1;
    const char* B0k0 = (const char*)Bsm0 + wn * 8192 + lrow + sw0;
    const char* B0k1 = (const char*)Bsm0 + wn * 8192 + lrow + sw1;
    const char* B1k0 = (const char*)Bsm1 + wn * 8192 + lrow + sw0;
    const char* B1k1 = (const char*)Bsm1 + wn * 8192 + lrow + sw1;

    // prologue: K-tile 0 -> buf0
    stage_tile(Ahi, rowA, 0, (char*)Asm0, tid);
    stage_tile(Bhi, rowB, 0, (char*)Bsm0, tid);
    asm volatile("s_waitcnt vmcnt(0)" ::: "memory");
    __builtin_amdgcn_s_barrier();

    for (int it = 0; it < NITER; ++it) {
        const int u1 = 2 * it + 1, u2 = 2 * it + 2;
        // tile 2it on buf0; stage tile 2it+1 -> buf1
        tile_step(A0k0, A0k1, B0k0, B0k1, (char*)Asm1, (char*)Bsm1,
                  SEL_A(u1), SEL_B(u1), K0OF(u1), rowA, rowB, tid, true, acc);
        // tile 2it+1 on buf1; stage tile 2it+2 -> buf0
        tile_step(A1k0, A1k1, B1k0, B1k1, (char*)Asm0, (char*)Bsm0,
                  SEL_A(u2), SEL_B(u2), K0OF(u2), rowA, rowB, tid,
                  it < NITER - 1, acc);
    }
#undef SEL_A
#undef SEL_B
#undef K0OF
}

// ---------------------------------------------------------------------------
// y = x * M  (B operand = Mt[n,k] = M[k,n]); split-precision 3-pass.
// grid 512 (1-D, XCD-swizzled): m-tile = lin>>2 (128), n-tile = lin&3 (4).
// ---------------------------------------------------------------------------
__global__ __launch_bounds__(512, 2) void gemm_y_256(
    const bf16_t* __restrict__ xh, const bf16_t* __restrict__ xl,
    const bf16_t* __restrict__ Mth, const bf16_t* __restrict__ Mtl,
    bf16_t* __restrict__ out_hi, bf16_t* __restrict__ out_lo)
{
    __shared__ __align__(16) bf16_t Asm[2][256 * 64];
    __shared__ __align__(16) bf16_t Bsm[2][256 * 64];
    const int tid = threadIdx.x;
    const int lane = tid & 63, wid = tid >> 6;
    const int wm = wid >> 2, wn = wid & 3;
    const int lin = (blockIdx.x & 7) * 64 + (blockIdx.x >> 3);
    const int m0 = (lin >> 2) * 256;
    const int n0 = (lin & 3) * 256;

    f32x4 acc[8][4] = {};
    kloop256(xh, xl, Mth, Mtl, m0, n0, tid, lane, wm, wn,
             Asm[0], Asm[1], Bsm[0], Bsm[1], acc);

    // epilogue: C/D frag layout col=lane&15, row=(lane>>4)*4+r
    const int rbase = (lane >> 4) * 4;
    const int cbase = lane & 15;
    #pragma unroll
    for (int fr = 0; fr < 8; ++fr) {
        #pragma unroll
        for (int fc = 0; fc < 4; ++fc) {
            const int n = n0 + wn * 64 + fc * 16 + cbase;
            #pragma unroll
            for (int r = 0; r < 4; ++r) {
                const int m = m0 + wm * 128 + fr * 16 + rbase + r;
                float vf = acc[fr][fc][r];
                bf16_t h = (bf16_t)vf;
                out_hi[(size_t)m * DD + n] = h;
                out_lo[(size_t)m * DD + n] = (bf16_t)(vf - (float)h);
            }
        }
    }
}

// ---------------------------------------------------------------------------
// Scores (per batch): s[b,srow] += sum_t tanh(y.x + alpha_s + beta_t + c)*v[t]
// grid 512 (XCD-swizzled): t-tile = lin&3, s-tile = (lin>>2)&3, b = lin>>4.
// ---------------------------------------------------------------------------
__global__ __launch_bounds__(512, 2) void gemm_scores_256(
    const bf16_t* __restrict__ yh, const bf16_t* __restrict__ yl,
    const bf16_t* __restrict__ xh, const bf16_t* __restrict__ xl,
    const float* __restrict__ v, const float* __restrict__ alpha,
    const float* __restrict__ beta, const float* __restrict__ cbuf,
    float* __restrict__ sbuf)
{
    __shared__ __align__(16) bf16_t Asm[2][256 * 64];
    __shared__ __align__(16) bf16_t Bsm[2][256 * 64];
    const int tid = threadIdx.x;
    const int lane = tid & 63, wid = tid >> 6;
    const int wm = wid >> 2, wn = wid & 3;
    const int lin = (blockIdx.x & 7) * 64 + (blockIdx.x >> 3);
    const int t0 = (lin & 3) * 256;
    const int s0 = ((lin >> 2) & 3) * 256;
    const int b  = lin >> 4;
    const size_t boff = (size_t)b * SS * DD;

    f32x4 acc[8][4] = {};
    kloop256(yh + boff, yl + boff, xh + boff, xl + boff, s0, t0,
             tid, lane, wm, wn, Asm[0], Asm[1], Bsm[0], Bsm[1], acc);

    // epilogue: tanh(score + alpha_s + beta_t + c)*v[t]; 16-lane col reduce.
    const float c0 = cbuf[0];
    const int rbase = (lane >> 4) * 4;
    const int cbase = lane & 15;
    float bet[4], vv[4];
    #pragma unroll
    for (int fc = 0; fc < 4; ++fc) {
        const int t = t0 + wn * 64 + fc * 16 + cbase;
        bet[fc] = beta[b * SS + t];
        vv[fc]  = v[t];
    }
    #pragma unroll
    for (int fr = 0; fr < 8; ++fr) {
        #pragma unroll
        for (int r = 0; r < 4; ++r) {
            const int srow = s0 + wm * 128 + fr * 16 + rbase + r;
            const float al = alpha[b * SS + srow] + c0;
            float p = 0.f;
            #pragma unroll
            for (int fc = 0; fc < 4; ++fc)
                p += tanhf(acc[fr][fc][r] + al + bet[fc]) * vv[fc];
            p += __shfl_xor(p, 1);
            p += __shfl_xor(p, 2);
            p += __shfl_xor(p, 4);
            p += __shfl_xor(p, 8);
            if (cbase == 0) atomicAdd(&sbuf[b * SS + srow], p);
        }
    }
}

// ---------------------------------------------------------------------------
// split fp32 -> (hi, lo) bf16.  hi = bf16(f), lo = bf16(f - hi).
// ---------------------------------------------------------------------------
__global__ __launch_bounds__(256) void split_fp32(
    const float* __restrict__ src, bf16_t* __restrict__ hi,
    bf16_t* __restrict__ lo, int n4)
{
    for (int idx = blockIdx.x * 256 + threadIdx.x; idx < n4;
         idx += gridDim.x * 256) {
        float4 f = ((const float4*)src)[idx];
        bf16x4 h, l;
        h.x = (bf16_t)f.x; h.y = (bf16_t)f.y; h.z = (bf16_t)f.z; h.w = (bf16_t)f.w;
        l.x = (bf16_t)(f.x - (float)h.x);
        l.y = (bf16_t)(f.y - (float)h.y);
        l.z = (bf16_t)(f.z - (float)h.z);
        l.w = (bf16_t)(f.w - (float)h.w);
        ((bf16x4*)hi)[idx] = h;
        ((bf16x4*)lo)[idx] = l;
    }
}

// ---------------------------------------------------------------------------
// split x -> hi/lo AND per-row alpha = x_row.avec, beta = x_row.bvec.
// Launch with grid = 2048 exactly (one row per block-iteration).
// ---------------------------------------------------------------------------
__global__ __launch_bounds__(256) void split_x_ab(
    const float* __restrict__ src, bf16_t* __restrict__ hi,
    bf16_t* __restrict__ lo, const float* __restrict__ avec,
    const float* __restrict__ bvec, float* __restrict__ alpha,
    float* __restrict__ beta)
{
    __shared__ float reda[4], redb[4];
    const int tid = threadIdx.x;
    const int lane = tid & 63, wave = tid >> 6;
    const float4 av = ((const float4*)avec)[tid];
    const float4 bv = ((const float4*)bvec)[tid];
    const int n4 = BB * SS * DD / 4;
    for (int idx = blockIdx.x * 256 + tid; idx < n4; idx += gridDim.x * 256) {
        float4 f = ((const float4*)src)[idx];
        bf16x4 h, l;
        h.x = (bf16_t)f.x; h.y = (bf16_t)f.y; h.z = (bf16_t)f.z; h.w = (bf16_t)f.w;
        l.x = (bf16_t)(f.x - (float)h.x);
        l.y = (bf16_t)(f.y - (float)h.y);
        l.z = (bf16_t)(f.z - (float)h.z);
        l.w = (bf16_t)(f.w - (float)h.w);
        ((bf16x4*)hi)[idx] = h;
        ((bf16x4*)lo)[idx] = l;

        float pa = f.x * av.x + f.y * av.y + f.z * av.z + f.w * av.w;
        float pb = f.x * bv.x + f.y * bv.y + f.z * bv.z + f.w * bv.w;
        #pragma unroll
        for (int off = 32; off; off >>= 1) {
            pa += __shfl_xor(pa, off);
            pb += __shfl_xor(pb, off);
        }
        if (lane == 0) { reda[wave] = pa; redb[wave] = pb; }
        __syncthreads();
        if (tid == 0) {
            const int row = idx >> 8;
            alpha[row] = reda[0] + reda[1] + reda[2] + reda[3];
            beta[row]  = redb[0] + redb[1] + redb[2] + redb[3];
        }
        __syncthreads();
    }
}

// ---------------------------------------------------------------------------
// avec[d] = sum_e Wq[e,d]*bk[e] (z=0), bvec[d] = sum_e Wk[e,d]*bq[e] (z=1).
// ---------------------------------------------------------------------------
__global__ __launch_bounds__(256) void bias_gemv(
    const float* __restrict__ Wq, const float* __restrict__ Wk,
    const float* __restrict__ bq, const float* __restrict__ bk,
    float* __restrict__ avec, float* __restrict__ bvec)
{
    const float* W   = blockIdx.z ? Wk : Wq;
    const float* bb  = blockIdx.z ? bq : bk;
    float* outv      = blockIdx.z ? bvec : avec;
    const int d  = blockIdx.x * 256 + threadIdx.x;
    const int e0 = blockIdx.y * 64;
    float s = 0.f;
    for (int e = e0; e < e0 + 64; ++e) s += W[(size_t)e * DD + d] * bb[e];
    atomicAdd(&outv[d], s);
}

__global__ __launch_bounds__(256) void dot_c(
    const float* __restrict__ bq, const float* __restrict__ bk,
    float* __restrict__ cbuf)
{
    __shared__ float red[4];
    const int tid = threadIdx.x, lane = tid & 63, wave = tid >> 6;
    float s = 0.f;
    for (int e = tid; e < DD; e += 256) s += bq[e] * bk[e];
    #pragma unroll
    for (int off = 32; off; off >>= 1) s += __shfl_xor(s, off);
    if (lane == 0) red[wave] = s;
    __syncthreads();
    if (tid == 0) cbuf[0] = red[0] + red[1] + red[2] + red[3];
}

// ---------------------------------------------------------------------------
// Mt[n,k] = sum_e Wk[e,n] * Wq[e,k]   (fp32 VALU, 64x64 tile)
// ---------------------------------------------------------------------------
__global__ __launch_bounds__(256) void mt_f32(
    const float* __restrict__ Wk, const float* __restrict__ Wq,
    float* __restrict__ Mt)
{
    __shared__ float Us[16][68];
    __shared__ float Vs[16][68];
    const int tid = threadIdx.x;
    const int tx = tid & 15, ty = tid >> 4;
    const int i0 = blockIdx.y * 64;
    const int j0 = blockIdx.x * 64;
    float acc[4][4] = {};
    for (int e0 = 0; e0 < DD; e0 += 16) {
        #pragma unroll
        for (int r = 0; r < 4; ++r) {
            const int kk = (tid >> 6) + r * 4;
            const int cc = tid & 63;
            Us[kk][cc] = Wk[(size_t)(e0 + kk) * DD + i0 + cc];
            Vs[kk][cc] = Wq[(size_t)(e0 + kk) * DD + j0 + cc];
        }
        __syncthreads();
        #pragma unroll
        for (int kk = 0; kk < 16; ++kk) {
            float4 a = *(const float4*)&Us[kk][ty * 4];
            float4 w = *(const float4*)&Vs[kk][tx * 4];
            acc[0][0] += a.x * w.x; acc[0][1] += a.x * w.y; acc[0][2] += a.x * w.z; acc[0][3] += a.x * w.w;
            acc[1][0] += a.y * w.x; acc[1][1] += a.y * w.y; acc[1][2] += a.y * w.z; acc[1][3] += a.y * w.w;
            acc[2][0] += a.z * w.x; acc[2][1] += a.z * w.y; acc[2][2] += a.z * w.z; acc[2][3] += a.z * w.w;
            acc[3][0] += a.w * w.x; acc[3][1] += a.w * w.y; acc[3][2] += a.w * w.z; acc[3][3] += a.w * w.w;
        }
        __syncthreads();
    }
    #pragma unroll
    for (int i = 0; i < 4; ++i)
        #pragma unroll
        for (int j = 0; j < 4; ++j)
            Mt[(size_t)(i0 + ty * 4 + i) * DD + j0 + tx * 4 + j] = acc[i][j];
}

// ---------------------------------------------------------------------------
// softmax over S per batch
// ---------------------------------------------------------------------------
__global__ __launch_bounds__(256) void softmax_rows(
    const float* __restrict__ sbuf, float* __restrict__ wbuf)
{
    const int b = blockIdx.x, tid = threadIdx.x;
    const int wave = tid >> 6, lane = tid & 63;
    __shared__ float redm[4];
    __shared__ float redsum[4];

    float vals[4];
    float mx = -1e30f;
    #pragma unroll
    for (int i = 0; i < 4; ++i) {
        vals[i] = sbuf[b * SS + i * 256 + tid];
        mx = fmaxf(mx, vals[i]);
    }
    #pragma unroll
    for (int off = 32; off; off >>= 1) mx = fmaxf(mx, __shfl_xor(mx, off));
    if (lane == 0) redm[wave] = mx;
    __syncthreads();
    mx = fmaxf(fmaxf(redm[0], redm[1]), fmaxf(redm[2], redm[3]));

    float sum = 0.f;
    #pragma unroll
    for (int i = 0; i < 4; ++i) { vals[i] = expf(vals[i] - mx); sum += vals[i]; }
    #pragma unroll
    for (int off = 32; off; off >>= 1) sum += __shfl_xor(sum, off);
    if (lane == 0) redsum[wave] = sum;
    __syncthreads();
    sum = redsum[0] + redsum[1] + redsum[2] + redsum[3];

    float inv = 1.0f / sum;
    #pragma unroll
    for (int i = 0; i < 4; ++i) wbuf[b * SS + i * 256 + tid] = vals[i] * inv;
}

// ---------------------------------------------------------------------------
// out[b,d] = sum_s w[b,s] * x[b,s,d]
// ---------------------------------------------------------------------------
__global__ __launch_bounds__(256) void weighted_sum(
    const float* __restrict__ x, const float* __restrict__ wbuf,
    float* __restrict__ out)
{
    __shared__ float wl[SS];
    const int b = blockIdx.y;
    const int d = blockIdx.x * 256 + threadIdx.x;
    for (int i = threadIdx.x; i < SS; i += 256) wl[i] = wbuf[b * SS + i];
    __syncthreads();

    const float* xb = x + (size_t)b * SS * DD + d;
    float acc = 0.f;
    for (int s = 0; s < SS; ++s) acc += wl[s] * xb[(size_t)s * DD];
    out[b * DD + d] = acc;
}

// ======================= round-1 fp32 fallback kernels ======================
__global__ __launch_bounds__(256) void linear_qk(
    const float* __restrict__ x, const float* __restrict__ W,
    const float* __restrict__ bias, float* __restrict__ y)
{
    __shared__ float As[16][68];
    __shared__ float Ws[16][68];
    const int tid = threadIdx.x;
    const int tx = tid & 15, ty = tid >> 4;
    const int m0 = blockIdx.y * 64;
    const int n0 = blockIdx.x * 64;
    float acc[4][4] = {};
    for (int k0 = 0; k0 < DD; k0 += 16) {
        #pragma unroll
        for (int i = 0; i < 4; ++i) {
            int idx = i * 256 + tid;
            int kk = idx & 15, mm = idx >> 4;
            As[kk][mm] = x[(size_t)(m0 + mm) * DD + (k0 + kk)];
            Ws[kk][mm] = W[(size_t)(n0 + mm) * DD + (k0 + kk)];
        }
        __syncthreads();
        #pragma unroll
        for (int kk = 0; kk < 16; ++kk) {
            float4 a = *(const float4*)&As[kk][ty * 4];
            float4 w = *(const float4*)&Ws[kk][tx * 4];
            acc[0][0] += a.x * w.x; acc[0][1] += a.x * w.y; acc[0][2] += a.x * w.z; acc[0][3] += a.x * w.w;
            acc[1][0] += a.y * w.x; acc[1][1] += a.y * w.y; acc[1][2] += a.y * w.z; acc[1][3] += a.y * w.w;
            acc[2][0] += a.z * w.x; acc[2][1] += a.z * w.y; acc[2][2] += a.z * w.z; acc[2][3] += a.z * w.w;
            acc[3][0] += a.w * w.x; acc[3][1] += a.w * w.y; acc[3][2] += a.w * w.z; acc[3][3] += a.w * w.w;
        }
        __syncthreads();
    }
    #pragma unroll
    for (int i = 0; i < 4; ++i) {
        int m = m0 + ty * 4 + i;
        #pragma unroll
        for (int j = 0; j < 4; ++j) {
            int n = n0 + tx * 4 + j;
            y[(size_t)m * DD + n] = acc[i][j] + bias[n];
        }
    }
}

__global__ __launch_bounds__(256) void scores_reduce(
    const float* __restrict__ q, const float* __restrict__ k,
    const float* __restrict__ v, float* __restrict__ s_out)
{
    __shared__ float As[16][68];
    __shared__ float Ws[16][68];
    __shared__ float red[64][17];
    const int tid = threadIdx.x;
    const int tx = tid & 15, ty = tid >> 4;
    const int b  = blockIdx.z;
    const int s0 = blockIdx.y * 64;
    const int t0 = blockIdx.x * 64;
    const float* qb = q + (size_t)b * SS * DD;
    const float* kb = k + (size_t)b * SS * DD;
    float acc[4][4] = {};
    for (int k0 = 0; k0 < DD; k0 += 16) {
        #pragma unroll
        for (int i = 0; i < 4; ++i) {
            int idx = i * 256 + tid;
            int kk = idx & 15, mm = idx >> 4;
            As[kk][mm] = qb[(size_t)(s0 + mm) * DD + (k0 + kk)];
            Ws[kk][mm] = kb[(size_t)(t0 + mm) * DD + (k0 + kk)];
        }
        __syncthreads();
        #pragma unroll
        for (int kk = 0; kk < 16; ++kk) {
            float4 a = *(const float4*)&As[kk][ty * 4];
            float4 w = *(const float4*)&Ws[kk][tx * 4];
            acc[0][0] += a.x * w.x; acc[0][1] += a.x * w.y; acc[0][2] += a.x * w.z; acc[0][3] += a.x * w.w;
            acc[1][0] += a.y * w.x; acc[1][1] += a.y * w.y; acc[1][2] += a.y * w.z; acc[1][3] += a.y * w.w;
            acc[2][0] += a.z * w.x; acc[2][1] += a.z * w.y; acc[2][2] += a.z * w.z; acc[2][3] += a.z * w.w;
            acc[3][0] += a.w * w.x; acc[3][1] += a.w * w.y; acc[3][2] += a.w * w.z; acc[3][3] += a.w * w.w;
        }
        __syncthreads();
    }
    float vj[4];
    #pragma unroll
    for (int j = 0; j < 4; ++j) vj[j] = v[t0 + tx * 4 + j];
    #pragma unroll
    for (int i = 0; i < 4; ++i) {
        float p = 0.f;
        #pragma unroll
        for (int j = 0; j < 4; ++j) p += tanhf(acc[i][j]) * vj[j];
        red[ty * 4 + i][tx] = p;
    }
    __syncthreads();
    if (tid < 64) {
        float tot = 0.f;
        #pragma unroll
        for (int c = 0; c < 16; ++c) tot += red[tid][c];
        atomicAdd(&s_out[b * SS + s0 + tid], tot);
    }
}

// ---------------------------------------------------------------------------
extern "C" void kernel_launch(void* const* d_in, const int* in_sizes, int n_in,
                              void* d_out, int out_size, void* d_ws, size_t ws_size,
                              hipStream_t stream) {
    const float* x  = (const float*)d_in[0];
    const float* Wq = (const float*)d_in[1];
    const float* bq = (const float*)d_in[2];
    const float* Wk = (const float*)d_in[3];
    const float* bk = (const float*)d_in[4];
    const float* v  = (const float*)d_in[5];
    float* out = (float*)d_out;

    const size_t nx = (size_t)BB * SS * DD;   // 33,554,432
    const size_t nw = (size_t)DD * DD;        // 1,048,576
    const size_t need = nx * 2 * 4 + nw * 4 + nw * 2 * 2 +
                        4096 * 2 + 16 + (size_t)BB * SS * 4 * 4;

    dim3 blk(256);

    if (ws_size >= need) {
        // ---- fast path: M = Wq^T Wk factorization + 2-phase split GEMMs ----
        char* p = (char*)d_ws;
        bf16_t* xh  = (bf16_t*)p;   p += nx * 2;
        bf16_t* xl  = (bf16_t*)p;   p += nx * 2;
        bf16_t* yh  = (bf16_t*)p;   p += nx * 2;
        bf16_t* yl  = (bf16_t*)p;   p += nx * 2;
        float*  Mt  = (float*)p;    p += nw * 4;
        bf16_t* Mth = (bf16_t*)p;   p += nw * 2;
        bf16_t* Mtl = (bf16_t*)p;   p += nw * 2;
        float*  avec = (float*)p;   p += 4096;
        float*  bvec = (float*)p;   p += 4096;
        float*  cbuf = (float*)p;   p += 16;
        float*  alpha = (float*)p;  p += (size_t)BB * SS * 4;
        float*  beta  = (float*)p;  p += (size_t)BB * SS * 4;
        float*  sbuf  = (float*)p;  p += (size_t)BB * SS * 4;
        float*  wbuf  = (float*)p;

        hipMemsetAsync(sbuf, 0, (size_t)BB * SS * sizeof(float), stream);
        hipMemsetAsync(avec, 0, 4096 * 2, stream);

        bias_gemv<<<dim3(4, 16, 2), blk, 0, stream>>>(Wq, Wk, bq, bk, avec, bvec);
        dot_c<<<1, blk, 0, stream>>>(bq, bk, cbuf);
        split_x_ab<<<2048, blk, 0, stream>>>(x, xh, xl, avec, bvec, alpha, beta);
        mt_f32<<<dim3(16, 16), blk, 0, stream>>>(Wk, Wq, Mt);
        split_fp32<<<512, blk, 0, stream>>>(Mt, Mth, Mtl, (int)(nw / 4));

        gemm_y_256<<<512, dim3(512), 0, stream>>>(xh, xl, Mth, Mtl, yh, yl);
        gemm_scores_256<<<512, dim3(512), 0, stream>>>(yh, yl, xh, xl, v,
                                                       alpha, beta, cbuf, sbuf);

        softmax_rows<<<BB, blk, 0, stream>>>(sbuf, wbuf);
        dim3 g4(DD / 256, BB);
        weighted_sum<<<g4, blk, 0, stream>>>(x, wbuf, out);
    } else {
        // ---- fallback: round-1 fp32 path ----
        float* q    = (float*)d_ws;
        float* kk   = q + nx;
        float* sbuf = kk + nx;
        float* wbuf = sbuf + BB * SS;

        hipMemsetAsync(sbuf, 0, (size_t)BB * SS * sizeof(float), stream);

        dim3 g1(DD / 64, (BB * SS) / 64);
        linear_qk<<<g1, blk, 0, stream>>>(x, Wq, bq, q);
        linear_qk<<<g1, blk, 0, stream>>>(x, Wk, bk, kk);
        dim3 g2(SS / 64, SS / 64, BB);
        scores_reduce<<<g2, blk, 0, stream>>>(q, kk, v, sbuf);
        softmax_rows<<<BB, blk, 0, stream>>>(sbuf, wbuf);
        dim3 g4(DD / 256, BB);
        weighted_sum<<<g4, blk, 0, stream>>>(x, wbuf, out);
    }
}

// Round 7
// 652.559 us; speedup vs baseline: 4.5586x; 1.0789x over previous
//
#include <hip/hip_runtime.h>
#include <hip/hip_bf16.h>
#include <math.h>

#define BB 32
#define SS 1024
#define DD 1024

typedef __bf16 bf16_t;
typedef __bf16 bf16x4 __attribute__((ext_vector_type(4)));
typedef __bf16 bf16x8 __attribute__((ext_vector_type(8)));
typedef float f32x4 __attribute__((ext_vector_type(4)));

// async global -> LDS, 16B per lane. LDS pointer must be wave-uniform;
// HW writes lds_base + lane*16 (linear).
__device__ __forceinline__ void gload16(const void* g, void* lds_uniform) {
    __builtin_amdgcn_global_load_lds(
        (const __attribute__((address_space(1))) void*)g,
        (__attribute__((address_space(3))) void*)lds_uniform, 16, 0, 0);
}

// ---------------------------------------------------------------------------
// Stage one 256x32 bf16 tile (16 KB) into an LDS slot: 2 gloads/thread.
// LDS layout row-major [256][64B]; thread t -> byte t*16 (row t>>2, chunk
// t&3) + second gload covers rows 128..255 at +8192. No swizzle needed:
// fragment reads (16 rows x 4 k-chunks across 64 lanes) cover 64 distinct
// 16B slots -> uniform bank usage.
// ---------------------------------------------------------------------------
__device__ __forceinline__ void stage32(const bf16_t* __restrict__ src,
                                        int row0, int k0, char* slot, int tid) {
    const int r = tid >> 2;
    const int c = (tid & 3) * 8;
    char* d = slot + (tid >> 6) * 1024;   // wave-uniform dest
    const bf16_t* s = src + (size_t)(row0 + r) * DD + k0 + c;
    gload16(s, d);
    gload16(s + (size_t)128 * DD, d + 8192);
}

#define VM8  asm volatile("s_waitcnt vmcnt(8)" ::: "memory")
#define VM4  asm volatile("s_waitcnt vmcnt(4)" ::: "memory")
#define VM0  asm volatile("s_waitcnt vmcnt(0)" ::: "memory")
#define BARR asm volatile("s_barrier" ::: "memory")

// pass selection over 96 K-tiles (3 split passes x 32 tiles of K=32):
// pass 0: Ah*Bh, pass 1: Ah*Bl, pass 2: Al*Bh
#define SEL_A(u) ((((u) >> 5) == 2) ? Alo : Ahi)
#define SEL_B(u) ((((u) >> 5) == 1) ? Blo : Bhi)
#define K0OF(u)  (((u) & 31) * 32)

// One K=32 tile on static slot s: stage A(u+3), read 4 B-frags + 4 A-frags,
// 16 MFMA, stage B(u+3), read 4 A-frags (rows 64..127), 16 MFMA.
// vmcnt/barrier appended by caller.
#define TILE32(u, s, DOST) do {                                               \
    if (DOST) stage32(SEL_A((u)+3), rowA, K0OF((u)+3),                        \
                      AslR + ((((u)+3)&3) * 16384), tid);                     \
    bf16x8 bfr[4], af[4];                                                     \
    _Pragma("unroll") for (int fc = 0; fc < 4; ++fc)                          \
        bfr[fc] = *(const bf16x8*)(Bbase##s + fc * 1024);                     \
    _Pragma("unroll") for (int fr = 0; fr < 4; ++fr)                          \
        af[fr] = *(const bf16x8*)(Abase##s + fr * 1024);                      \
    _Pragma("unroll") for (int fr = 0; fr < 4; ++fr)                          \
        _Pragma("unroll") for (int fc = 0; fc < 4; ++fc)                      \
            acc[fr][fc] = __builtin_amdgcn_mfma_f32_16x16x32_bf16(            \
                af[fr], bfr[fc], acc[fr][fc], 0, 0, 0);                       \
    if (DOST) stage32(SEL_B((u)+3), rowB, K0OF((u)+3),                        \
                      BslR + ((((u)+3)&3) * 16384), tid);                     \
    _Pragma("unroll") for (int fr = 0; fr < 4; ++fr)                          \
        af[fr] = *(const bf16x8*)(Abase##s + 4096 + fr * 1024);               \
    _Pragma("unroll") for (int fr = 0; fr < 4; ++fr)                          \
        _Pragma("unroll") for (int fc = 0; fc < 4; ++fc)                      \
            acc[4+fr][fc] = __builtin_amdgcn_mfma_f32_16x16x32_bf16(          \
                af[fr], bfr[fc], acc[4+fr][fc], 0, 0, 0);                     \
} while (0)

// ---------------------------------------------------------------------------
// 96-K-tile ring loop (4 slots, prefetch depth 3, counted vmcnt).
// Ring discipline: stage(u+3) targets slot (u-1)&3 whose reads finished
// before tile (u-1)'s closing barrier; vmcnt(8) at tile u's end waits only
// for tile u+1's 4 gloads (issued during tile u-2).
// ---------------------------------------------------------------------------
__device__ __forceinline__ void kloop_ring(
    const bf16_t* __restrict__ Ahi, const bf16_t* __restrict__ Alo,
    const bf16_t* __restrict__ Bhi, const bf16_t* __restrict__ Blo,
    int rowA, int rowB, int tid, int lane, int wm, int wn,
    char* AslR, char* BslR, f32x4 (*acc)[4])
{
    // per-lane read base: row (lane&15), k-chunk (lane>>4)
    const int aoff = (lane & 15) * 64 + (lane >> 4) * 16;
    const char* Abase0 = AslR + wm * 8192 + aoff;
    const char* Abase1 = Abase0 + 16384;
    const char* Abase2 = Abase0 + 32768;
    const char* Abase3 = Abase0 + 49152;
    const char* Bbase0 = BslR + wn * 4096 + aoff;
    const char* Bbase1 = Bbase0 + 16384;
    const char* Bbase2 = Bbase0 + 32768;
    const char* Bbase3 = Bbase0 + 49152;

    // prologue: stage tiles 0,1,2 into slots 0,1,2 (12 gloads in flight)
    stage32(SEL_A(0), rowA, K0OF(0), AslR, tid);
    stage32(SEL_B(0), rowB, K0OF(0), BslR, tid);
    stage32(SEL_A(1), rowA, K0OF(1), AslR + 16384, tid);
    stage32(SEL_B(1), rowB, K0OF(1), BslR + 16384, tid);
    stage32(SEL_A(2), rowA, K0OF(2), AslR + 32768, tid);
    stage32(SEL_B(2), rowB, K0OF(2), BslR + 32768, tid);
    VM8;   // tile 0 landed (8 = tiles 1,2 still outstanding)
    BARR;

    for (int i = 0; i < 23; ++i) {
        const int u0 = i * 4;
        TILE32(u0 + 0, 0, true); VM8; BARR;
        TILE32(u0 + 1, 1, true); VM8; BARR;
        TILE32(u0 + 2, 2, true); VM8; BARR;
        TILE32(u0 + 3, 3, true); VM8; BARR;
    }
    // tail: tiles 92..95 (92 stages tile 95; then drain 8 -> 4 -> 0)
    TILE32(92, 0, true);  VM8; BARR;
    TILE32(93, 1, false); VM4; BARR;
    TILE32(94, 2, false); VM0; BARR;
    TILE32(95, 3, false);
}

// ---------------------------------------------------------------------------
// y = x * M  (B operand = Mt[n,k] = M[k,n]); split-precision 3-pass.
// grid 512 (1-D, XCD-swizzled): m-tile = lin>>2 (128), n-tile = lin&3 (4).
// ---------------------------------------------------------------------------
__global__ __launch_bounds__(512, 2) void gemm_y_256(
    const bf16_t* __restrict__ xh, const bf16_t* __restrict__ xl,
    const bf16_t* __restrict__ Mth, const bf16_t* __restrict__ Mtl,
    bf16_t* __restrict__ out_hi, bf16_t* __restrict__ out_lo)
{
    __shared__ __align__(16) bf16_t Asl[4][256 * 32];
    __shared__ __align__(16) bf16_t Bsl[4][256 * 32];
    const int tid = threadIdx.x;
    const int lane = tid & 63, wid = tid >> 6;
    const int wm = wid >> 2, wn = wid & 3;
    const int lin = (blockIdx.x & 7) * 64 + (blockIdx.x >> 3);
    const int m0 = (lin >> 2) * 256;
    const int n0 = (lin & 3) * 256;

    f32x4 acc[8][4] = {};
    kloop_ring(xh, xl, Mth, Mtl, m0, n0, tid, lane, wm, wn,
               (char*)Asl, (char*)Bsl, acc);

    // epilogue: C/D frag layout col=lane&15, row=(lane>>4)*4+r
    const int rbase = (lane >> 4) * 4;
    const int cbase = lane & 15;
    #pragma unroll
    for (int fr = 0; fr < 8; ++fr) {
        #pragma unroll
        for (int fc = 0; fc < 4; ++fc) {
            const int n = n0 + wn * 64 + fc * 16 + cbase;
            #pragma unroll
            for (int r = 0; r < 4; ++r) {
                const int m = m0 + wm * 128 + fr * 16 + rbase + r;
                float vf = acc[fr][fc][r];
                bf16_t h = (bf16_t)vf;
                out_hi[(size_t)m * DD + n] = h;
                out_lo[(size_t)m * DD + n] = (bf16_t)(vf - (float)h);
            }
        }
    }
}

// ---------------------------------------------------------------------------
// Scores (per batch): s[b,srow] += sum_t tanh(y.x + alpha_s + beta_t + c)*v[t]
// grid 512 (XCD-swizzled): t-tile = lin&3, s-tile = (lin>>2)&3, b = lin>>4.
// ---------------------------------------------------------------------------
__global__ __launch_bounds__(512, 2) void gemm_scores_256(
    const bf16_t* __restrict__ yh, const bf16_t* __restrict__ yl,
    const bf16_t* __restrict__ xh, const bf16_t* __restrict__ xl,
    const float* __restrict__ v, const float* __restrict__ alpha,
    const float* __restrict__ beta, const float* __restrict__ cbuf,
    float* __restrict__ sbuf)
{
    __shared__ __align__(16) bf16_t Asl[4][256 * 32];
    __shared__ __align__(16) bf16_t Bsl[4][256 * 32];
    const int tid = threadIdx.x;
    const int lane = tid & 63, wid = tid >> 6;
    const int wm = wid >> 2, wn = wid & 3;
    const int lin = (blockIdx.x & 7) * 64 + (blockIdx.x >> 3);
    const int t0 = (lin & 3) * 256;
    const int s0 = ((lin >> 2) & 3) * 256;
    const int b  = lin >> 4;
    const size_t boff = (size_t)b * SS * DD;

    f32x4 acc[8][4] = {};
    kloop_ring(yh + boff, yl + boff, xh + boff, xl + boff, s0, t0,
               tid, lane, wm, wn, (char*)Asl, (char*)Bsl, acc);

    // epilogue: tanh(score + alpha_s + beta_t + c)*v[t]; 16-lane col reduce.
    const float c0 = cbuf[0];
    const int rbase = (lane >> 4) * 4;
    const int cbase = lane & 15;
    float bet[4], vv[4];
    #pragma unroll
    for (int fc = 0; fc < 4; ++fc) {
        const int t = t0 + wn * 64 + fc * 16 + cbase;
        bet[fc] = beta[b * SS + t];
        vv[fc]  = v[t];
    }
    #pragma unroll
    for (int fr = 0; fr < 8; ++fr) {
        #pragma unroll
        for (int r = 0; r < 4; ++r) {
            const int srow = s0 + wm * 128 + fr * 16 + rbase + r;
            const float al = alpha[b * SS + srow] + c0;
            float p = 0.f;
            #pragma unroll
            for (int fc = 0; fc < 4; ++fc)
                p += tanhf(acc[fr][fc][r] + al + bet[fc]) * vv[fc];
            p += __shfl_xor(p, 1);
            p += __shfl_xor(p, 2);
            p += __shfl_xor(p, 4);
            p += __shfl_xor(p, 8);
            if (cbase == 0) atomicAdd(&sbuf[b * SS + srow], p);
        }
    }
}

// ---------------------------------------------------------------------------
// split fp32 -> (hi, lo) bf16.  hi = bf16(f), lo = bf16(f - hi).
// ---------------------------------------------------------------------------
__global__ __launch_bounds__(256) void split_fp32(
    const float* __restrict__ src, bf16_t* __restrict__ hi,
    bf16_t* __restrict__ lo, int n4)
{
    for (int idx = blockIdx.x * 256 + threadIdx.x; idx < n4;
         idx += gridDim.x * 256) {
        float4 f = ((const float4*)src)[idx];
        bf16x4 h, l;
        h.x = (bf16_t)f.x; h.y = (bf16_t)f.y; h.z = (bf16_t)f.z; h.w = (bf16_t)f.w;
        l.x = (bf16_t)(f.x - (float)h.x);
        l.y = (bf16_t)(f.y - (float)h.y);
        l.z = (bf16_t)(f.z - (float)h.z);
        l.w = (bf16_t)(f.w - (float)h.w);
        ((bf16x4*)hi)[idx] = h;
        ((bf16x4*)lo)[idx] = l;
    }
}

// ---------------------------------------------------------------------------
// split x -> hi/lo AND per-row alpha = x_row.avec, beta = x_row.bvec.
// Launch with grid = 2048 exactly (one row per block-iteration).
// ---------------------------------------------------------------------------
__global__ __launch_bounds__(256) void split_x_ab(
    const float* __restrict__ src, bf16_t* __restrict__ hi,
    bf16_t* __restrict__ lo, const float* __restrict__ avec,
    const float* __restrict__ bvec, float* __restrict__ alpha,
    float* __restrict__ beta)
{
    __shared__ float reda[4], redb[4];
    const int tid = threadIdx.x;
    const int lane = tid & 63, wave = tid >> 6;
    const float4 av = ((const float4*)avec)[tid];
    const float4 bv = ((const float4*)bvec)[tid];
    const int n4 = BB * SS * DD / 4;
    for (int idx = blockIdx.x * 256 + tid; idx < n4; idx += gridDim.x * 256) {
        float4 f = ((const float4*)src)[idx];
        bf16x4 h, l;
        h.x = (bf16_t)f.x; h.y = (bf16_t)f.y; h.z = (bf16_t)f.z; h.w = (bf16_t)f.w;
        l.x = (bf16_t)(f.x - (float)h.x);
        l.y = (bf16_t)(f.y - (float)h.y);
        l.z = (bf16_t)(f.z - (float)h.z);
        l.w = (bf16_t)(f.w - (float)h.w);
        ((bf16x4*)hi)[idx] = h;
        ((bf16x4*)lo)[idx] = l;

        float pa = f.x * av.x + f.y * av.y + f.z * av.z + f.w * av.w;
        float pb = f.x * bv.x + f.y * bv.y + f.z * bv.z + f.w * bv.w;
        #pragma unroll
        for (int off = 32; off; off >>= 1) {
            pa += __shfl_xor(pa, off);
            pb += __shfl_xor(pb, off);
        }
        if (lane == 0) { reda[wave] = pa; redb[wave] = pb; }
        __syncthreads();
        if (tid == 0) {
            const int row = idx >> 8;
            alpha[row] = reda[0] + reda[1] + reda[2] + reda[3];
            beta[row]  = redb[0] + redb[1] + redb[2] + redb[3];
        }
        __syncthreads();
    }
}

// ---------------------------------------------------------------------------
// avec[d] = sum_e Wq[e,d]*bk[e] (z=0), bvec[d] = sum_e Wk[e,d]*bq[e] (z=1).
// ---------------------------------------------------------------------------
__global__ __launch_bounds__(256) void bias_gemv(
    const float* __restrict__ Wq, const float* __restrict__ Wk,
    const float* __restrict__ bq, const float* __restrict__ bk,
    float* __restrict__ avec, float* __restrict__ bvec)
{
    const float* W   = blockIdx.z ? Wk : Wq;
    const float* bb  = blockIdx.z ? bq : bk;
    float* outv      = blockIdx.z ? bvec : avec;
    const int d  = blockIdx.x * 256 + threadIdx.x;
    const int e0 = blockIdx.y * 64;
    float s = 0.f;
    for (int e = e0; e < e0 + 64; ++e) s += W[(size_t)e * DD + d] * bb[e];
    atomicAdd(&outv[d], s);
}

__global__ __launch_bounds__(256) void dot_c(
    const float* __restrict__ bq, const float* __restrict__ bk,
    float* __restrict__ cbuf)
{
    __shared__ float red[4];
    const int tid = threadIdx.x, lane = tid & 63, wave = tid >> 6;
    float s = 0.f;
    for (int e = tid; e < DD; e += 256) s += bq[e] * bk[e];
    #pragma unroll
    for (int off = 32; off; off >>= 1) s += __shfl_xor(s, off);
    if (lane == 0) red[wave] = s;
    __syncthreads();
    if (tid == 0) cbuf[0] = red[0] + red[1] + red[2] + red[3];
}

// ---------------------------------------------------------------------------
// Mt[n,k] = sum_e Wk[e,n] * Wq[e,k]   (fp32 VALU, 64x64 tile)
// ---------------------------------------------------------------------------
__global__ __launch_bounds__(256) void mt_f32(
    const float* __restrict__ Wk, const float* __restrict__ Wq,
    float* __restrict__ Mt)
{
    __shared__ float Us[16][68];
    __shared__ float Vs[16][68];
    const int tid = threadIdx.x;
    const int tx = tid & 15, ty = tid >> 4;
    const int i0 = blockIdx.y * 64;
    const int j0 = blockIdx.x * 64;
    float acc[4][4] = {};
    for (int e0 = 0; e0 < DD; e0 += 16) {
        #pragma unroll
        for (int r = 0; r < 4; ++r) {
            const int kk = (tid >> 6) + r * 4;
            const int cc = tid & 63;
            Us[kk][cc] = Wk[(size_t)(e0 + kk) * DD + i0 + cc];
            Vs[kk][cc] = Wq[(size_t)(e0 + kk) * DD + j0 + cc];
        }
        __syncthreads();
        #pragma unroll
        for (int kk = 0; kk < 16; ++kk) {
            float4 a = *(const float4*)&Us[kk][ty * 4];
            float4 w = *(const float4*)&Vs[kk][tx * 4];
            acc[0][0] += a.x * w.x; acc[0][1] += a.x * w.y; acc[0][2] += a.x * w.z; acc[0][3] += a.x * w.w;
            acc[1][0] += a.y * w.x; acc[1][1] += a.y * w.y; acc[1][2] += a.y * w.z; acc[1][3] += a.y * w.w;
            acc[2][0] += a.z * w.x; acc[2][1] += a.z * w.y; acc[2][2] += a.z * w.z; acc[2][3] += a.z * w.w;
            acc[3][0] += a.w * w.x; acc[3][1] += a.w * w.y; acc[3][2] += a.w * w.z; acc[3][3] += a.w * w.w;
        }
        __syncthreads();
    }
    #pragma unroll
    for (int i = 0; i < 4; ++i)
        #pragma unroll
        for (int j = 0; j < 4; ++j)
            Mt[(size_t)(i0 + ty * 4 + i) * DD + j0 + tx * 4 + j] = acc[i][j];
}

// ---------------------------------------------------------------------------
// softmax over S per batch
// ---------------------------------------------------------------------------
__global__ __launch_bounds__(256) void softmax_rows(
    const float* __restrict__ sbuf, float* __restrict__ wbuf)
{
    const int b = blockIdx.x, tid = threadIdx.x;
    const int wave = tid >> 6, lane = tid & 63;
    __shared__ float redm[4];
    __shared__ float redsum[4];

    float vals[4];
    float mx = -1e30f;
    #pragma unroll
    for (int i = 0; i < 4; ++i) {
        vals[i] = sbuf[b * SS + i * 256 + tid];
        mx = fmaxf(mx, vals[i]);
    }
    #pragma unroll
    for (int off = 32; off; off >>= 1) mx = fmaxf(mx, __shfl_xor(mx, off));
    if (lane == 0) redm[wave] = mx;
    __syncthreads();
    mx = fmaxf(fmaxf(redm[0], redm[1]), fmaxf(redm[2], redm[3]));

    float sum = 0.f;
    #pragma unroll
    for (int i = 0; i < 4; ++i) { vals[i] = expf(vals[i] - mx); sum += vals[i]; }
    #pragma unroll
    for (int off = 32; off; off >>= 1) sum += __shfl_xor(sum, off);
    if (lane == 0) redsum[wave] = sum;
    __syncthreads();
    sum = redsum[0] + redsum[1] + redsum[2] + redsum[3];

    float inv = 1.0f / sum;
    #pragma unroll
    for (int i = 0; i < 4; ++i) wbuf[b * SS + i * 256 + tid] = vals[i] * inv;
}

// ---------------------------------------------------------------------------
// out[b,d] = sum_s w[b,s] * x[b,s,d]
// ---------------------------------------------------------------------------
__global__ __launch_bounds__(256) void weighted_sum(
    const float* __restrict__ x, const float* __restrict__ wbuf,
    float* __restrict__ out)
{
    __shared__ float wl[SS];
    const int b = blockIdx.y;
    const int d = blockIdx.x * 256 + threadIdx.x;
    for (int i = threadIdx.x; i < SS; i += 256) wl[i] = wbuf[b * SS + i];
    __syncthreads();

    const float* xb = x + (size_t)b * SS * DD + d;
    float acc = 0.f;
    for (int s = 0; s < SS; ++s) acc += wl[s] * xb[(size_t)s * DD];
    out[b * DD + d] = acc;
}

// ======================= round-1 fp32 fallback kernels ======================
__global__ __launch_bounds__(256) void linear_qk(
    const float* __restrict__ x, const float* __restrict__ W,
    const float* __restrict__ bias, float* __restrict__ y)
{
    __shared__ float As[16][68];
    __shared__ float Ws[16][68];
    const int tid = threadIdx.x;
    const int tx = tid & 15, ty = tid >> 4;
    const int m0 = blockIdx.y * 64;
    const int n0 = blockIdx.x * 64;
    float acc[4][4] = {};
    for (int k0 = 0; k0 < DD; k0 += 16) {
        #pragma unroll
        for (int i = 0; i < 4; ++i) {
            int idx = i * 256 + tid;
            int kk = idx & 15, mm = idx >> 4;
            As[kk][mm] = x[(size_t)(m0 + mm) * DD + (k0 + kk)];
            Ws[kk][mm] = W[(size_t)(n0 + mm) * DD + (k0 + kk)];
        }
        __syncthreads();
        #pragma unroll
        for (int kk = 0; kk < 16; ++kk) {
            float4 a = *(const float4*)&As[kk][ty * 4];
            float4 w = *(const float4*)&Ws[kk][tx * 4];
            acc[0][0] += a.x * w.x; acc[0][1] += a.x * w.y; acc[0][2] += a.x * w.z; acc[0][3] += a.x * w.w;
            acc[1][0] += a.y * w.x; acc[1][1] += a.y * w.y; acc[1][2] += a.y * w.z; acc[1][3] += a.y * w.w;
            acc[2][0] += a.z * w.x; acc[2][1] += a.z * w.y; acc[2][2] += a.z * w.z; acc[2][3] += a.z * w.w;
            acc[3][0] += a.w * w.x; acc[3][1] += a.w * w.y; acc[3][2] += a.w * w.z; acc[3][3] += a.w * w.w;
        }
        __syncthreads();
    }
    #pragma unroll
    for (int i = 0; i < 4; ++i) {
        int m = m0 + ty * 4 + i;
        #pragma unroll
        for (int j = 0; j < 4; ++j) {
            int n = n0 + tx * 4 + j;
            y[(size_t)m * DD + n] = acc[i][j] + bias[n];
        }
    }
}

__global__ __launch_bounds__(256) void scores_reduce(
    const float* __restrict__ q, const float* __restrict__ k,
    const float* __restrict__ v, float* __restrict__ s_out)
{
    __shared__ float As[16][68];
    __shared__ float Ws[16][68];
    __shared__ float red[64][17];
    const int tid = threadIdx.x;
    const int tx = tid & 15, ty = tid >> 4;
    const int b  = blockIdx.z;
    const int s0 = blockIdx.y * 64;
    const int t0 = blockIdx.x * 64;
    const float* qb = q + (size_t)b * SS * DD;
    const float* kb = k + (size_t)b * SS * DD;
    float acc[4][4] = {};
    for (int k0 = 0; k0 < DD; k0 += 16) {
        #pragma unroll
        for (int i = 0; i < 4; ++i) {
            int idx = i * 256 + tid;
            int kk = idx & 15, mm = idx >> 4;
            As[kk][mm] = qb[(size_t)(s0 + mm) * DD + (k0 + kk)];
            Ws[kk][mm] = kb[(size_t)(t0 + mm) * DD + (k0 + kk)];
        }
        __syncthreads();
        #pragma unroll
        for (int kk = 0; kk < 16; ++kk) {
            float4 a = *(const float4*)&As[kk][ty * 4];
            float4 w = *(const float4*)&Ws[kk][tx * 4];
            acc[0][0] += a.x * w.x; acc[0][1] += a.x * w.y; acc[0][2] += a.x * w.z; acc[0][3] += a.x * w.w;
            acc[1][0] += a.y * w.x; acc[1][1] += a.y * w.y; acc[1][2] += a.y * w.z; acc[1][3] += a.y * w.w;
            acc[2][0] += a.z * w.x; acc[2][1] += a.z * w.y; acc[2][2] += a.z * w.z; acc[2][3] += a.z * w.w;
            acc[3][0] += a.w * w.x; acc[3][1] += a.w * w.y; acc[3][2] += a.w * w.z; acc[3][3] += a.w * w.w;
        }
        __syncthreads();
    }
    float vj[4];
    #pragma unroll
    for (int j = 0; j < 4; ++j) vj[j] = v[t0 + tx * 4 + j];
    #pragma unroll
    for (int i = 0; i < 4; ++i) {
        float p = 0.f;
        #pragma unroll
        for (int j = 0; j < 4; ++j) p += tanhf(acc[i][j]) * vj[j];
        red[ty * 4 + i][tx] = p;
    }
    __syncthreads();
    if (tid < 64) {
        float tot = 0.f;
        #pragma unroll
        for (int c = 0; c < 16; ++c) tot += red[tid][c];
        atomicAdd(&s_out[b * SS + s0 + tid], tot);
    }
}

// ---------------------------------------------------------------------------
extern "C" void kernel_launch(void* const* d_in, const int* in_sizes, int n_in,
                              void* d_out, int out_size, void* d_ws, size_t ws_size,
                              hipStream_t stream) {
    const float* x  = (const float*)d_in[0];
    const float* Wq = (const float*)d_in[1];
    const float* bq = (const float*)d_in[2];
    const float* Wk = (const float*)d_in[3];
    const float* bk = (const float*)d_in[4];
    const float* v  = (const float*)d_in[5];
    float* out = (float*)d_out;

    const size_t nx = (size_t)BB * SS * DD;   // 33,554,432
    const size_t nw = (size_t)DD * DD;        // 1,048,576
    const size_t need = nx * 2 * 4 + nw * 4 + nw * 2 * 2 +
                        4096 * 2 + 16 + (size_t)BB * SS * 4 * 4;

    dim3 blk(256);

    if (ws_size >= need) {
        // ---- fast path: M = Wq^T Wk factorization + ring-4 split GEMMs ----
        char* p = (char*)d_ws;
        bf16_t* xh  = (bf16_t*)p;   p += nx * 2;
        bf16_t* xl  = (bf16_t*)p;   p += nx * 2;
        bf16_t* yh  = (bf16_t*)p;   p += nx * 2;
        bf16_t* yl  = (bf16_t*)p;   p += nx * 2;
        float*  Mt  = (float*)p;    p += nw * 4;
        bf16_t* Mth = (bf16_t*)p;   p += nw * 2;
        bf16_t* Mtl = (bf16_t*)p;   p += nw * 2;
        float*  avec = (float*)p;   p += 4096;
        float*  bvec = (float*)p;   p += 4096;
        float*  cbuf = (float*)p;   p += 16;
        float*  alpha = (float*)p;  p += (size_t)BB * SS * 4;
        float*  beta  = (float*)p;  p += (size_t)BB * SS * 4;
        float*  sbuf  = (float*)p;  p += (size_t)BB * SS * 4;
        float*  wbuf  = (float*)p;

        hipMemsetAsync(sbuf, 0, (size_t)BB * SS * sizeof(float), stream);
        hipMemsetAsync(avec, 0, 4096 * 2, stream);

        bias_gemv<<<dim3(4, 16, 2), blk, 0, stream>>>(Wq, Wk, bq, bk, avec, bvec);
        dot_c<<<1, blk, 0, stream>>>(bq, bk, cbuf);
        split_x_ab<<<2048, blk, 0, stream>>>(x, xh, xl, avec, bvec, alpha, beta);
        mt_f32<<<dim3(16, 16), blk, 0, stream>>>(Wk, Wq, Mt);
        split_fp32<<<512, blk, 0, stream>>>(Mt, Mth, Mtl, (int)(nw / 4));

        gemm_y_256<<<512, dim3(512), 0, stream>>>(xh, xl, Mth, Mtl, yh, yl);
        gemm_scores_256<<<512, dim3(512), 0, stream>>>(yh, yl, xh, xl, v,
                                                       alpha, beta, cbuf, sbuf);

        softmax_rows<<<BB, blk, 0, stream>>>(sbuf, wbuf);
        dim3 g4(DD / 256, BB);
        weighted_sum<<<g4, blk, 0, stream>>>(x, wbuf, out);
    } else {
        // ---- fallback: round-1 fp32 path ----
        float* q    = (float*)d_ws;
        float* kk   = q + nx;
        float* sbuf = kk + nx;
        float* wbuf = sbuf + BB * SS;

        hipMemsetAsync(sbuf, 0, (size_t)BB * SS * sizeof(float), stream);

        dim3 g1(DD / 64, (BB * SS) / 64);
        linear_qk<<<g1, blk, 0, stream>>>(x, Wq, bq, q);
        linear_qk<<<g1, blk, 0, stream>>>(x, Wk, bk, kk);
        dim3 g2(SS / 64, SS / 64, BB);
        scores_reduce<<<g2, blk, 0, stream>>>(q, kk, v, sbuf);
        softmax_rows<<<BB, blk, 0, stream>>>(sbuf, wbuf);
        dim3 g4(DD / 256, BB);
        weighted_sum<<<g4, blk, 0, stream>>>(x, wbuf, out);
    }
}

// Round 8
// 650.525 us; speedup vs baseline: 4.5728x; 1.0031x over previous
//
#include <hip/hip_runtime.h>
#include <hip/hip_bf16.h>
#include <math.h>

#define BB 32
#define SS 1024
#define DD 1024

typedef __bf16 bf16_t;
typedef __bf16 bf16x4 __attribute__((ext_vector_type(4)));
typedef __bf16 bf16x8 __attribute__((ext_vector_type(8)));
typedef float f32x4 __attribute__((ext_vector_type(4)));

// async global -> LDS, 16B per lane. LDS pointer must be wave-uniform;
// HW writes lds_base + lane*16 (linear).
__device__ __forceinline__ void gload16(const void* g, void* lds_uniform) {
    __builtin_amdgcn_global_load_lds(
        (const __attribute__((address_space(1))) void*)g,
        (__attribute__((address_space(3))) void*)lds_uniform, 16, 0, 0);
}

// ---------------------------------------------------------------------------
// Stage one 256x32 bf16 tile (16 KB) into an LDS slot: 2 gloads/thread.
// LDS layout row-major [256][64B = 4 chunks of 16B], chunk-XOR swizzled:
// LDS slot (row, c) holds global chunk c ^ ((row>>1)&3). Write side
// pre-swizzles the global source (LDS dest stays linear: thread t -> byte
// t*16 = row t>>2, chunk t&3; source chunk = (t&3) ^ ((t>>3)&3)).
// Second gload covers rows +128: (row+128)>>1 & 3 unchanged (64&3==0).
// Bank check: slot index mod 128B = (r&1)*4 + (g ^ ((r>>1)&3)) covers all
// 8 slots exactly twice per 16-lane group -> 2-way (free, m136).
// ---------------------------------------------------------------------------
__device__ __forceinline__ void stage32(const bf16_t* __restrict__ src,
                                        int row0, int k0, char* slot, int tid) {
    const int r = tid >> 2;
    const int c = ((tid & 3) ^ ((tid >> 3) & 3)) * 8;   // swizzled source chunk
    char* d = slot + (tid >> 6) * 1024;   // wave-uniform dest
    const bf16_t* s = src + (size_t)(row0 + r) * DD + k0 + c;
    gload16(s, d);
    gload16(s + (size_t)128 * DD, d + 8192);
}

#define VM8  asm volatile("s_waitcnt vmcnt(8)" ::: "memory")
#define VM4  asm volatile("s_waitcnt vmcnt(4)" ::: "memory")
#define VM0  asm volatile("s_waitcnt vmcnt(0)" ::: "memory")
#define BARR asm volatile("s_barrier" ::: "memory")

// pass selection over 96 K-tiles (3 split passes x 32 tiles of K=32):
// pass 0: Ah*Bh, pass 1: Ah*Bl, pass 2: Al*Bh
#define SEL_A(u) ((((u) >> 5) == 2) ? Alo : Ahi)
#define SEL_B(u) ((((u) >> 5) == 1) ? Blo : Bhi)
#define K0OF(u)  (((u) & 31) * 32)

// One K=32 tile on static slot s: stage A(u+3), read 4 B-frags + 4 A-frags,
// 16 MFMA, stage B(u+3), read 4 A-frags (rows 64..127), 16 MFMA.
// vmcnt/barrier appended by caller.
#define TILE32(u, s, DOST) do {                                               \
    if (DOST) stage32(SEL_A((u)+3), rowA, K0OF((u)+3),                        \
                      AslR + ((((u)+3)&3) * 16384), tid);                     \
    bf16x8 bfr[4], af[4];                                                     \
    _Pragma("unroll") for (int fc = 0; fc < 4; ++fc)                          \
        bfr[fc] = *(const bf16x8*)(Bbase##s + fc * 1024);                     \
    _Pragma("unroll") for (int fr = 0; fr < 4; ++fr)                          \
        af[fr] = *(const bf16x8*)(Abase##s + fr * 1024);                      \
    _Pragma("unroll") for (int fr = 0; fr < 4; ++fr)                          \
        _Pragma("unroll") for (int fc = 0; fc < 4; ++fc)                      \
            acc[fr][fc] = __builtin_amdgcn_mfma_f32_16x16x32_bf16(            \
                af[fr], bfr[fc], acc[fr][fc], 0, 0, 0);                       \
    if (DOST) stage32(SEL_B((u)+3), rowB, K0OF((u)+3),                        \
                      BslR + ((((u)+3)&3) * 16384), tid);                     \
    _Pragma("unroll") for (int fr = 0; fr < 4; ++fr)                          \
        af[fr] = *(const bf16x8*)(Abase##s + 4096 + fr * 1024);               \
    _Pragma("unroll") for (int fr = 0; fr < 4; ++fr)                          \
        _Pragma("unroll") for (int fc = 0; fc < 4; ++fc)                      \
            acc[4+fr][fc] = __builtin_amdgcn_mfma_f32_16x16x32_bf16(          \
                af[fr], bfr[fc], acc[4+fr][fc], 0, 0, 0);                     \
} while (0)

// ---------------------------------------------------------------------------
// 96-K-tile ring loop (4 slots, prefetch depth 3, counted vmcnt).
// Ring discipline: stage(u+3) targets slot (u-1)&3 whose reads finished
// before tile (u-1)'s closing barrier; vmcnt(8) at tile u's end waits only
// for tile u+1's 4 gloads (issued during tile u-2).
// ---------------------------------------------------------------------------
__device__ __forceinline__ void kloop_ring(
    const bf16_t* __restrict__ Ahi, const bf16_t* __restrict__ Alo,
    const bf16_t* __restrict__ Bhi, const bf16_t* __restrict__ Blo,
    int rowA, int rowB, int tid, int lane, int wm, int wn,
    char* AslR, char* BslR, f32x4 (*acc)[4])
{
    // per-lane read base: row (lane&15), k-chunk (lane>>4), chunk-XOR swizzle
    const int aoff = (lane & 15) * 64 + (((lane >> 4) ^ ((lane >> 1) & 3)) * 16);
    const char* Abase0 = AslR + wm * 8192 + aoff;
    const char* Abase1 = Abase0 + 16384;
    const char* Abase2 = Abase0 + 32768;
    const char* Abase3 = Abase0 + 49152;
    const char* Bbase0 = BslR + wn * 4096 + aoff;
    const char* Bbase1 = Bbase0 + 16384;
    const char* Bbase2 = Bbase0 + 32768;
    const char* Bbase3 = Bbase0 + 49152;

    // prologue: stage tiles 0,1,2 into slots 0,1,2 (12 gloads in flight)
    stage32(SEL_A(0), rowA, K0OF(0), AslR, tid);
    stage32(SEL_B(0), rowB, K0OF(0), BslR, tid);
    stage32(SEL_A(1), rowA, K0OF(1), AslR + 16384, tid);
    stage32(SEL_B(1), rowB, K0OF(1), BslR + 16384, tid);
    stage32(SEL_A(2), rowA, K0OF(2), AslR + 32768, tid);
    stage32(SEL_B(2), rowB, K0OF(2), BslR + 32768, tid);
    VM8;   // tile 0 landed (8 = tiles 1,2 still outstanding)
    BARR;

    for (int i = 0; i < 23; ++i) {
        const int u0 = i * 4;
        TILE32(u0 + 0, 0, true); VM8; BARR;
        TILE32(u0 + 1, 1, true); VM8; BARR;
        TILE32(u0 + 2, 2, true); VM8; BARR;
        TILE32(u0 + 3, 3, true); VM8; BARR;
    }
    // tail: tiles 92..95 (92 stages tile 95; then drain 8 -> 4 -> 0)
    TILE32(92, 0, true);  VM8; BARR;
    TILE32(93, 1, false); VM4; BARR;
    TILE32(94, 2, false); VM0; BARR;
    TILE32(95, 3, false);
}

// ---------------------------------------------------------------------------
// y = x * M  (B operand = Mt[n,k] = M[k,n]); split-precision 3-pass.
// grid 512 (1-D, XCD-swizzled): m-tile = lin>>2 (128), n-tile = lin&3 (4).
// ---------------------------------------------------------------------------
__global__ __launch_bounds__(512, 2) void gemm_y_256(
    const bf16_t* __restrict__ xh, const bf16_t* __restrict__ xl,
    const bf16_t* __restrict__ Mth, const bf16_t* __restrict__ Mtl,
    bf16_t* __restrict__ out_hi, bf16_t* __restrict__ out_lo)
{
    __shared__ __align__(16) bf16_t Asl[4][256 * 32];
    __shared__ __align__(16) bf16_t Bsl[4][256 * 32];
    const int tid = threadIdx.x;
    const int lane = tid & 63, wid = tid >> 6;
    const int wm = wid >> 2, wn = wid & 3;
    const int lin = (blockIdx.x & 7) * 64 + (blockIdx.x >> 3);
    const int m0 = (lin >> 2) * 256;
    const int n0 = (lin & 3) * 256;

    f32x4 acc[8][4] = {};
    kloop_ring(xh, xl, Mth, Mtl, m0, n0, tid, lane, wm, wn,
               (char*)Asl, (char*)Bsl, acc);

    // epilogue: C/D frag layout col=lane&15, row=(lane>>4)*4+r
    const int rbase = (lane >> 4) * 4;
    const int cbase = lane & 15;
    #pragma unroll
    for (int fr = 0; fr < 8; ++fr) {
        #pragma unroll
        for (int fc = 0; fc < 4; ++fc) {
            const int n = n0 + wn * 64 + fc * 16 + cbase;
            #pragma unroll
            for (int r = 0; r < 4; ++r) {
                const int m = m0 + wm * 128 + fr * 16 + rbase + r;
                float vf = acc[fr][fc][r];
                bf16_t h = (bf16_t)vf;
                out_hi[(size_t)m * DD + n] = h;
                out_lo[(size_t)m * DD + n] = (bf16_t)(vf - (float)h);
            }
        }
    }
}

// ---------------------------------------------------------------------------
// Scores (per batch): s[b,srow] += sum_t tanh(y.x + alpha_s + beta_t + c)*v[t]
// grid 512 (XCD-swizzled): t-tile = lin&3, s-tile = (lin>>2)&3, b = lin>>4.
// ---------------------------------------------------------------------------
__global__ __launch_bounds__(512, 2) void gemm_scores_256(
    const bf16_t* __restrict__ yh, const bf16_t* __restrict__ yl,
    const bf16_t* __restrict__ xh, const bf16_t* __restrict__ xl,
    const float* __restrict__ v, const float* __restrict__ alpha,
    const float* __restrict__ beta, const float* __restrict__ cbuf,
    float* __restrict__ sbuf)
{
    __shared__ __align__(16) bf16_t Asl[4][256 * 32];
    __shared__ __align__(16) bf16_t Bsl[4][256 * 32];
    const int tid = threadIdx.x;
    const int lane = tid & 63, wid = tid >> 6;
    const int wm = wid >> 2, wn = wid & 3;
    const int lin = (blockIdx.x & 7) * 64 + (blockIdx.x >> 3);
    const int t0 = (lin & 3) * 256;
    const int s0 = ((lin >> 2) & 3) * 256;
    const int b  = lin >> 4;
    const size_t boff = (size_t)b * SS * DD;

    f32x4 acc[8][4] = {};
    kloop_ring(yh + boff, yl + boff, xh + boff, xl + boff, s0, t0,
               tid, lane, wm, wn, (char*)Asl, (char*)Bsl, acc);

    // epilogue: tanh(score + alpha_s + beta_t + c)*v[t]; 16-lane col reduce.
    const float c0 = cbuf[0];
    const int rbase = (lane >> 4) * 4;
    const int cbase = lane & 15;
    float bet[4], vv[4];
    #pragma unroll
    for (int fc = 0; fc < 4; ++fc) {
        const int t = t0 + wn * 64 + fc * 16 + cbase;
        bet[fc] = beta[b * SS + t];
        vv[fc]  = v[t];
    }
    #pragma unroll
    for (int fr = 0; fr < 8; ++fr) {
        #pragma unroll
        for (int r = 0; r < 4; ++r) {
            const int srow = s0 + wm * 128 + fr * 16 + rbase + r;
            const float al = alpha[b * SS + srow] + c0;
            float p = 0.f;
            #pragma unroll
            for (int fc = 0; fc < 4; ++fc)
                p += tanhf(acc[fr][fc][r] + al + bet[fc]) * vv[fc];
            p += __shfl_xor(p, 1);
            p += __shfl_xor(p, 2);
            p += __shfl_xor(p, 4);
            p += __shfl_xor(p, 8);
            if (cbase == 0) atomicAdd(&sbuf[b * SS + srow], p);
        }
    }
}

// ---------------------------------------------------------------------------
// split fp32 -> (hi, lo) bf16.  hi = bf16(f), lo = bf16(f - hi).
// ---------------------------------------------------------------------------
__global__ __launch_bounds__(256) void split_fp32(
    const float* __restrict__ src, bf16_t* __restrict__ hi,
    bf16_t* __restrict__ lo, int n4)
{
    for (int idx = blockIdx.x * 256 + threadIdx.x; idx < n4;
         idx += gridDim.x * 256) {
        float4 f = ((const float4*)src)[idx];
        bf16x4 h, l;
        h.x = (bf16_t)f.x; h.y = (bf16_t)f.y; h.z = (bf16_t)f.z; h.w = (bf16_t)f.w;
        l.x = (bf16_t)(f.x - (float)h.x);
        l.y = (bf16_t)(f.y - (float)h.y);
        l.z = (bf16_t)(f.z - (float)h.z);
        l.w = (bf16_t)(f.w - (float)h.w);
        ((bf16x4*)hi)[idx] = h;
        ((bf16x4*)lo)[idx] = l;
    }
}

// ---------------------------------------------------------------------------
// split x -> hi/lo AND per-row alpha = x_row.avec, beta = x_row.bvec.
// Launch with grid = 2048 exactly (one row per block-iteration).
// ---------------------------------------------------------------------------
__global__ __launch_bounds__(256) void split_x_ab(
    const float* __restrict__ src, bf16_t* __restrict__ hi,
    bf16_t* __restrict__ lo, const float* __restrict__ avec,
    const float* __restrict__ bvec, float* __restrict__ alpha,
    float* __restrict__ beta)
{
    __shared__ float reda[4], redb[4];
    const int tid = threadIdx.x;
    const int lane = tid & 63, wave = tid >> 6;
    const float4 av = ((const float4*)avec)[tid];
    const float4 bv = ((const float4*)bvec)[tid];
    const int n4 = BB * SS * DD / 4;
    for (int idx = blockIdx.x * 256 + tid; idx < n4; idx += gridDim.x * 256) {
        float4 f = ((const float4*)src)[idx];
        bf16x4 h, l;
        h.x = (bf16_t)f.x; h.y = (bf16_t)f.y; h.z = (bf16_t)f.z; h.w = (bf16_t)f.w;
        l.x = (bf16_t)(f.x - (float)h.x);
        l.y = (bf16_t)(f.y - (float)h.y);
        l.z = (bf16_t)(f.z - (float)h.z);
        l.w = (bf16_t)(f.w - (float)h.w);
        ((bf16x4*)hi)[idx] = h;
        ((bf16x4*)lo)[idx] = l;

        float pa = f.x * av.x + f.y * av.y + f.z * av.z + f.w * av.w;
        float pb = f.x * bv.x + f.y * bv.y + f.z * bv.z + f.w * bv.w;
        #pragma unroll
        for (int off = 32; off; off >>= 1) {
            pa += __shfl_xor(pa, off);
            pb += __shfl_xor(pb, off);
        }
        if (lane == 0) { reda[wave] = pa; redb[wave] = pb; }
        __syncthreads();
        if (tid == 0) {
            const int row = idx >> 8;
            alpha[row] = reda[0] + reda[1] + reda[2] + reda[3];
            beta[row]  = redb[0] + redb[1] + redb[2] + redb[3];
        }
        __syncthreads();
    }
}

// ---------------------------------------------------------------------------
// avec[d] = sum_e Wq[e,d]*bk[e] (z=0), bvec[d] = sum_e Wk[e,d]*bq[e] (z=1).
// ---------------------------------------------------------------------------
__global__ __launch_bounds__(256) void bias_gemv(
    const float* __restrict__ Wq, const float* __restrict__ Wk,
    const float* __restrict__ bq, const float* __restrict__ bk,
    float* __restrict__ avec, float* __restrict__ bvec)
{
    const float* W   = blockIdx.z ? Wk : Wq;
    const float* bb  = blockIdx.z ? bq : bk;
    float* outv      = blockIdx.z ? bvec : avec;
    const int d  = blockIdx.x * 256 + threadIdx.x;
    const int e0 = blockIdx.y * 64;
    float s = 0.f;
    for (int e = e0; e < e0 + 64; ++e) s += W[(size_t)e * DD + d] * bb[e];
    atomicAdd(&outv[d], s);
}

__global__ __launch_bounds__(256) void dot_c(
    const float* __restrict__ bq, const float* __restrict__ bk,
    float* __restrict__ cbuf)
{
    __shared__ float red[4];
    const int tid = threadIdx.x, lane = tid & 63, wave = tid >> 6;
    float s = 0.f;
    for (int e = tid; e < DD; e += 256) s += bq[e] * bk[e];
    #pragma unroll
    for (int off = 32; off; off >>= 1) s += __shfl_xor(s, off);
    if (lane == 0) red[wave] = s;
    __syncthreads();
    if (tid == 0) cbuf[0] = red[0] + red[1] + red[2] + red[3];
}

// ---------------------------------------------------------------------------
// Mt[n,k] = sum_e Wk[e,n] * Wq[e,k]   (fp32 VALU, 64x64 tile)
// ---------------------------------------------------------------------------
__global__ __launch_bounds__(256) void mt_f32(
    const float* __restrict__ Wk, const float* __restrict__ Wq,
    float* __restrict__ Mt)
{
    __shared__ float Us[16][68];
    __shared__ float Vs[16][68];
    const int tid = threadIdx.x;
    const int tx = tid & 15, ty = tid >> 4;
    const int i0 = blockIdx.y * 64;
    const int j0 = blockIdx.x * 64;
    float acc[4][4] = {};
    for (int e0 = 0; e0 < DD; e0 += 16) {
        #pragma unroll
        for (int r = 0; r < 4; ++r) {
            const int kk = (tid >> 6) + r * 4;
            const int cc = tid & 63;
            Us[kk][cc] = Wk[(size_t)(e0 + kk) * DD + i0 + cc];
            Vs[kk][cc] = Wq[(size_t)(e0 + kk) * DD + j0 + cc];
        }
        __syncthreads();
        #pragma unroll
        for (int kk = 0; kk < 16; ++kk) {
            float4 a = *(const float4*)&Us[kk][ty * 4];
            float4 w = *(const float4*)&Vs[kk][tx * 4];
            acc[0][0] += a.x * w.x; acc[0][1] += a.x * w.y; acc[0][2] += a.x * w.z; acc[0][3] += a.x * w.w;
            acc[1][0] += a.y * w.x; acc[1][1] += a.y * w.y; acc[1][2] += a.y * w.z; acc[1][3] += a.y * w.w;
            acc[2][0] += a.z * w.x; acc[2][1] += a.z * w.y; acc[2][2] += a.z * w.z; acc[2][3] += a.z * w.w;
            acc[3][0] += a.w * w.x; acc[3][1] += a.w * w.y; acc[3][2] += a.w * w.z; acc[3][3] += a.w * w.w;
        }
        __syncthreads();
    }
    #pragma unroll
    for (int i = 0; i < 4; ++i)
        #pragma unroll
        for (int j = 0; j < 4; ++j)
            Mt[(size_t)(i0 + ty * 4 + i) * DD + j0 + tx * 4 + j] = acc[i][j];
}

// ---------------------------------------------------------------------------
// softmax over S per batch
// ---------------------------------------------------------------------------
__global__ __launch_bounds__(256) void softmax_rows(
    const float* __restrict__ sbuf, float* __restrict__ wbuf)
{
    const int b = blockIdx.x, tid = threadIdx.x;
    const int wave = tid >> 6, lane = tid & 63;
    __shared__ float redm[4];
    __shared__ float redsum[4];

    float vals[4];
    float mx = -1e30f;
    #pragma unroll
    for (int i = 0; i < 4; ++i) {
        vals[i] = sbuf[b * SS + i * 256 + tid];
        mx = fmaxf(mx, vals[i]);
    }
    #pragma unroll
    for (int off = 32; off; off >>= 1) mx = fmaxf(mx, __shfl_xor(mx, off));
    if (lane == 0) redm[wave] = mx;
    __syncthreads();
    mx = fmaxf(fmaxf(redm[0], redm[1]), fmaxf(redm[2], redm[3]));

    float sum = 0.f;
    #pragma unroll
    for (int i = 0; i < 4; ++i) { vals[i] = expf(vals[i] - mx); sum += vals[i]; }
    #pragma unroll
    for (int off = 32; off; off >>= 1) sum += __shfl_xor(sum, off);
    if (lane == 0) redsum[wave] = sum;
    __syncthreads();
    sum = redsum[0] + redsum[1] + redsum[2] + redsum[3];

    float inv = 1.0f / sum;
    #pragma unroll
    for (int i = 0; i < 4; ++i) wbuf[b * SS + i * 256 + tid] = vals[i] * inv;
}

// ---------------------------------------------------------------------------
// out[b,d] = sum_s w[b,s] * x[b,s,d]
// ---------------------------------------------------------------------------
__global__ __launch_bounds__(256) void weighted_sum(
    const float* __restrict__ x, const float* __restrict__ wbuf,
    float* __restrict__ out)
{
    __shared__ float wl[SS];
    const int b = blockIdx.y;
    const int d = blockIdx.x * 256 + threadIdx.x;
    for (int i = threadIdx.x; i < SS; i += 256) wl[i] = wbuf[b * SS + i];
    __syncthreads();

    const float* xb = x + (size_t)b * SS * DD + d;
    float acc = 0.f;
    for (int s = 0; s < SS; ++s) acc += wl[s] * xb[(size_t)s * DD];
    out[b * DD + d] = acc;
}

// ---------------------------------------------------------------------------
extern "C" void kernel_launch(void* const* d_in, const int* in_sizes, int n_in,
                              void* d_out, int out_size, void* d_ws, size_t ws_size,
                              hipStream_t stream) {
    const float* x  = (const float*)d_in[0];
    const float* Wq = (const float*)d_in[1];
    const float* bq = (const float*)d_in[2];
    const float* Wk = (const float*)d_in[3];
    const float* bk = (const float*)d_in[4];
    const float* v  = (const float*)d_in[5];
    float* out = (float*)d_out;

    const size_t nx = (size_t)BB * SS * DD;   // 33,554,432
    const size_t nw = (size_t)DD * DD;        // 1,048,576

    dim3 blk(256);

    // workspace layout (verified to fit in rounds 4-7)
    char* p = (char*)d_ws;
    bf16_t* xh  = (bf16_t*)p;   p += nx * 2;
    bf16_t* xl  = (bf16_t*)p;   p += nx * 2;
    bf16_t* yh  = (bf16_t*)p;   p += nx * 2;
    bf16_t* yl  = (bf16_t*)p;   p += nx * 2;
    float*  Mt  = (float*)p;    p += nw * 4;
    bf16_t* Mth = (bf16_t*)p;   p += nw * 2;
    bf16_t* Mtl = (bf16_t*)p;   p += nw * 2;
    float*  avec = (float*)p;   p += 4096;
    float*  bvec = (float*)p;   p += 4096;
    float*  cbuf = (float*)p;   p += 16;
    float*  alpha = (float*)p;  p += (size_t)BB * SS * 4;
    float*  beta  = (float*)p;  p += (size_t)BB * SS * 4;
    float*  sbuf  = (float*)p;  p += (size_t)BB * SS * 4;
    float*  wbuf  = (float*)p;

    hipMemsetAsync(sbuf, 0, (size_t)BB * SS * sizeof(float), stream);
    hipMemsetAsync(avec, 0, 4096 * 2, stream);

    bias_gemv<<<dim3(4, 16, 2), blk, 0, stream>>>(Wq, Wk, bq, bk, avec, bvec);
    dot_c<<<1, blk, 0, stream>>>(bq, bk, cbuf);
    split_x_ab<<<2048, blk, 0, stream>>>(x, xh, xl, avec, bvec, alpha, beta);
    mt_f32<<<dim3(16, 16), blk, 0, stream>>>(Wk, Wq, Mt);
    split_fp32<<<512, blk, 0, stream>>>(Mt, Mth, Mtl, (int)(nw / 4));

    gemm_y_256<<<512, dim3(512), 0, stream>>>(xh, xl, Mth, Mtl, yh, yl);
    gemm_scores_256<<<512, dim3(512), 0, stream>>>(yh, yl, xh, xl, v,
                                                   alpha, beta, cbuf, sbuf);

    softmax_rows<<<BB, blk, 0, stream>>>(sbuf, wbuf);
    dim3 g4(DD / 256, BB);
    weighted_sum<<<g4, blk, 0, stream>>>(x, wbuf, out);
}